// Round 3
// baseline (20248.264 us; speedup 1.0000x reference)
//
#include <hip/hip_runtime.h>
#include <hip/hip_bf16.h>

#define XSTR 28   // BN LDS row stride (floats), 16B aligned

__device__ __forceinline__ float gelu_f(float x){
    return 0.5f*x*(1.0f + erff(x*0.70710678118654752f));
}

__device__ __forceinline__ unsigned short f2bf(float f){
    unsigned int u = __float_as_uint(f);
    u += 0x7fffu + ((u>>16)&1u);
    return (unsigned short)(u>>16);
}
__device__ __forceinline__ unsigned int pack2(float a, float b){
    return (unsigned int)f2bf(a) | ((unsigned int)f2bf(b)<<16);
}
__device__ __forceinline__ float bf_lo(unsigned int u){ return __uint_as_float(u<<16); }
__device__ __forceinline__ float bf_hi(unsigned int u){ return __uint_as_float(u & 0xffff0000u); }

// acc[0..24] += row[0..24] * w   (row is 16B-aligned LDS, broadcast across wave)
__device__ __forceinline__ void fma_row25(const float* __restrict__ row, float w, float* __restrict__ acc){
    const float4* r4 = (const float4*)row;
    float4 a0=r4[0], a1=r4[1], a2=r4[2], a3=r4[3], a4=r4[4], a5=r4[5];
    float a6 = row[24];
    acc[0]+=a0.x*w;  acc[1]+=a0.y*w;  acc[2]+=a0.z*w;  acc[3]+=a0.w*w;
    acc[4]+=a1.x*w;  acc[5]+=a1.y*w;  acc[6]+=a1.z*w;  acc[7]+=a1.w*w;
    acc[8]+=a2.x*w;  acc[9]+=a2.y*w;  acc[10]+=a2.z*w; acc[11]+=a2.w*w;
    acc[12]+=a3.x*w; acc[13]+=a3.y*w; acc[14]+=a3.z*w; acc[15]+=a3.w*w;
    acc[16]+=a4.x*w; acc[17]+=a4.y*w; acc[18]+=a4.z*w; acc[19]+=a4.w*w;
    acc[20]+=a5.x*w; acc[21]+=a5.y*w; acc[22]+=a5.z*w; acc[23]+=a5.w*w;
    acc[24]+=a6*w;
}

// ---------------- BN (bottleneck) branch: one block per sample, 59KB static LDS ----------------
__global__ __launch_bounds__(256,2) void bn_branch_kernel(
    const float* __restrict__ bottleneck,   // [256,128,128]
    const float* __restrict__ pos,          // [N,2] vis coords
    const float* __restrict__ dw_w, const float* __restrict__ dw_b,
    const float* __restrict__ ln_g, const float* __restrict__ ln_b,
    const float* __restrict__ pw1_w, const float* __restrict__ pw1_b,
    const float* __restrict__ pw2_w, const float* __restrict__ pw2_b,
    const float* __restrict__ cn_gamma,
    const float* __restrict__ bn1x1_w, const float* __restrict__ bn1x1_b,
    float* __restrict__ vec_out)            // [N,192], writes [0:128]
{
    __shared__ float xln[256*XSTR];   // dw out -> normalized -> (reused) final features
    __shared__ float hbuf[256*XSTR];  // one 256-row tile of pw1 activations
    __shared__ float redA[200], redB[200];
    __shared__ float mu[25], rs[25];

    const int n = blockIdx.x;
    const int t = threadIdx.x;
    const int c = t;                  // thread = channel

    const float px = pos[2*n]*0.125f, py = pos[2*n+1]*0.125f;
    const float fpx = floorf(px), fpy = floorf(py);
    const int ix0 = (int)fpx - 2, iy0 = (int)fpy - 2;
    const float fx = px - fpx, fy = py - fpy;
    const float w00=(1.f-fy)*(1.f-fx), w01=(1.f-fy)*fx, w10=fy*(1.f-fx), w11=fy*fx;

    // ---- gather 6x6 patch, blend to 5x5 window (kept in regs for residual) ----
    float wv[25];
    {
        const float* fm = bottleneck + c*16384;
        float P[6][6];
        #pragma unroll
        for (int r=0;r<6;r++){
            const int y = iy0+r;
            const bool yok = (y>=0)&&(y<128);
            const int yc = y<0?0:(y>127?127:y);
            #pragma unroll
            for (int s=0;s<6;s++){
                const int x = ix0+s;
                const bool ok = yok && (x>=0) && (x<128);
                const int xc = x<0?0:(x>127?127:x);
                P[r][s] = ok ? fm[yc*128+xc] : 0.f;
            }
        }
        #pragma unroll
        for (int a=0;a<5;a++)
        #pragma unroll
        for (int b=0;b<5;b++)
            wv[a*5+b] = w00*P[a][b]+w01*P[a][b+1]+w10*P[a+1][b]+w11*P[a+1][b+1];
    }
    // ---- depthwise 7x7 (zero padded 5x5) -> xln ----
    {
        float wcr[49];
        const float* wc = dw_w + c*49;
        #pragma unroll
        for (int k=0;k<49;k++) wcr[k]=wc[k];
        const float bb = dw_b[c];
        #pragma unroll
        for (int i=0;i<5;i++){
            #pragma unroll
            for (int j=0;j<5;j++){
                float a = bb;
                #pragma unroll
                for (int u=0;u<7;u++){
                    const int y = i+u-3;
                    if (y<0||y>4) continue;
                    #pragma unroll
                    for (int v=0;v<7;v++){
                        const int x = j+v-3;
                        if (x<0||x>4) continue;
                        a += wv[y*5+x]*wcr[u*7+v];
                    }
                }
                xln[c*XSTR + i*5+j] = a;
            }
        }
    }
    __syncthreads();
    // ---- LayerNorm stats over channels, 8 partials per position ----
    if (t < 200){
        const int p = t>>3, s = t&7;
        float a=0.f, b=0.f;
        for (int cc=s; cc<256; cc+=8){
            const float v = xln[cc*XSTR+p];
            a += v; b += v*v;
        }
        redA[t]=a; redB[t]=b;
    }
    __syncthreads();
    if (t < 25){
        float a=0.f, b=0.f;
        #pragma unroll
        for (int s=0;s<8;s++){ a+=redA[t*8+s]; b+=redB[t*8+s]; }
        const float m = a*(1.f/256.f);
        const float var = b*(1.f/256.f) - m*m;
        mu[t]=m; rs[t]=rsqrtf(var+1e-6f);
    }
    __syncthreads();
    {
        const float g = ln_g[c], bb = ln_b[c];
        #pragma unroll
        for (int p=0;p<25;p++)
            xln[c*XSTR+p] = (xln[c*XSTR+p]-mu[p])*rs[p]*g + bb;
    }
    __syncthreads();
    // ---- pw1 (256->1024, gelu) and pw2 (1024->256) tiled in 4 rounds of 256 ----
    float acc2[25];
    #pragma unroll
    for (int p=0;p<25;p++) acc2[p]=0.f;
    for (int r=0;r<4;r++){
        const int o = r*256 + t;
        float h[25];
        {
            const float b1 = pw1_b[o];
            #pragma unroll
            for (int p=0;p<25;p++) h[p]=b1;
            const float* wr = pw1_w + o*256;
            for (int cc=0;cc<256;cc++)
                fma_row25(xln + cc*XSTR, wr[cc], h);
            #pragma unroll
            for (int p=0;p<25;p++) h[p]=gelu_f(h[p]);
        }
        __syncthreads();   // previous round's hbuf reads are done
        #pragma unroll
        for (int p=0;p<25;p++) hbuf[t*XSTR+p]=h[p];
        __syncthreads();
        {
            const float* w2 = pw2_w + t*1024 + r*256;
            for (int k=0;k<256;k++)
                fma_row25(hbuf + k*XSTR, w2[k], acc2);
        }
    }
    // ---- residual + gamma -> reuse xln as final feature buffer ----
    {
        const float gam = cn_gamma[c], b2 = pw2_b[c];
        #pragma unroll
        for (int p=0;p<25;p++)
            xln[c*XSTR+p] = wv[p] + gam*(acc2[p]+b2);
    }
    __syncthreads();
    // ---- 1x1 conv 256->128 + gelu + separable gauss(5) ----
    if (t < 128){
        float acc[25];
        #pragma unroll
        for (int p=0;p<25;p++) acc[p]=0.f;
        const float* wr = bn1x1_w + t*256;
        for (int cc=0;cc<256;cc++)
            fma_row25(xln + cc*XSTR, wr[cc], acc);
        const float b = bn1x1_b[t];
        float e5[5];
        #pragma unroll
        for (int a=0;a<5;a++){
            const float ta = -1.f + 0.5f*a;
            e5[a] = expf(-3.125f*ta*ta);
        }
        const float Sv = e5[0]+e5[1]+e5[2]+e5[3]+e5[4];
        float res = 0.f;
        #pragma unroll
        for (int a=0;a<5;a++){
            float rowa = 0.f;
            #pragma unroll
            for (int bb=0;bb<5;bb++)
                rowa += e5[bb]*gelu_f(acc[a*5+bb]+b);
            res += e5[a]*rowa;
        }
        vec_out[n*192+t] = res/(Sv*Sv);
    }
}

// ---------------- stem conv weight transpose: [o][c][9] -> [c][o][9] ----------------
__global__ __launch_bounds__(256) void transpose_w_kernel(
    const float* __restrict__ s1, const float* __restrict__ s2,
    float* __restrict__ t1, float* __restrict__ t2)
{
    int idx = blockIdx.x*256 + threadIdx.x;   // 2*36864
    const float* s = s1; float* d = t1;
    if (idx >= 36864){ idx -= 36864; s = s2; d = t2; }
    const int cpair = idx/576;          // c
    const int rem = idx - cpair*576;
    const int o = rem/9, k = rem - o*9;
    d[idx] = s[(o*64+cpair)*9 + k];
}

// ---------------- Stem branch: one block per sample, 79KB static LDS ----------------
__device__ __forceinline__ void load_row19(const unsigned int* __restrict__ rowp, float* __restrict__ r){
    r[0]=0.f;
    #pragma unroll
    for (int k=0;k<9;k++){
        const unsigned int u = rowp[k];
        r[1+2*k] = bf_lo(u);
        r[2+2*k] = bf_hi(u);   // k==8 hi is the stored zero pad (col 17)
    }
}
__device__ __forceinline__ void zero_row19(float* __restrict__ r){
    #pragma unroll
    for (int k=0;k<19;k++) r[k]=0.f;
}

template<bool TR>
__global__ __launch_bounds__(256,2) void stem_branch_kernel(
    const float* __restrict__ vis,   // [64,1024,1024]
    const float* __restrict__ pos,
    const float* __restrict__ W1, const float* __restrict__ st1_b,
    const float* __restrict__ W2, const float* __restrict__ st2_b,
    float* __restrict__ vec_out)     // [N,192], writes [128:192]
{
    __shared__ unsigned int win[64*153];   // bf16x2 packed, row=9 u32 (17 cols + pad)
    __shared__ unsigned int c1 [64*153];
    __shared__ float redS[256];

    const int n = blockIdx.x;
    const int t = threadIdx.x;
    const float px = pos[2*n], py = pos[2*n+1];
    const float fpx = floorf(px), fpy = floorf(py);
    const int ix0 = (int)fpx - 8, iy0 = (int)fpy - 8;
    const float fx = px-fpx, fy = py-fpy;
    const float w00=(1.f-fy)*(1.f-fx), w01=(1.f-fy)*fx, w10=fy*(1.f-fx), w11=fy*fx;

    // ---- blend 17x17 windows directly from global (all in-bounds: pos in [10,1014)) ----
    for (int idx=t; idx<64*153; idx+=256){
        const int cch = idx/153;
        const int rem = idx - cch*153;
        const int i = rem/9, kp = rem - i*9;
        const int b0 = 2*kp;
        const float* pr = vis + cch*1048576 + (iy0+i)*1024 + (ix0+b0);
        const float q00=pr[0],   q01=pr[1],   q02=pr[2];
        const float q10=pr[1024],q11=pr[1025],q12=pr[1026];
        const float v0 = w00*q00 + w01*q01 + w10*q10 + w11*q11;
        float v1 = w00*q01 + w01*q02 + w10*q11 + w11*q12;
        if (kp==8) v1 = 0.f;
        win[idx] = pack2(v0, v1);
    }
    __syncthreads();

    const int o   = t & 63;
    const int wid = t >> 6;
    const int base = (wid==0) ? 0 : (1 + 4*wid);  // rows: 0-4,5-8,9-12,13-16
    const int nr   = (wid==0) ? 5 : 4;

    // ---- conv1 (64->64, 3x3, gelu) ----
    {
        float acc[5][17];
        const float bo = st1_b[o];
        #pragma unroll
        for (int rr=0;rr<5;rr++)
            #pragma unroll
            for (int j=0;j<17;j++) acc[rr][j]=bo;
        for (int cc=0;cc<64;cc++){
            const float* wp = TR ? (W1 + (cc*64+o)*9) : (W1 + (o*64+cc)*9);
            float w[9];
            #pragma unroll
            for (int k=0;k<9;k++) w[k]=wp[k];
            const unsigned int* plane = win + cc*153;
            #pragma unroll
            for (int rr=0;rr<5;rr++){
                if (rr < nr){
                    const int i = base+rr;
                    float rm[19], r0[19], rp[19];
                    if (i>0)  load_row19(plane+(i-1)*9, rm); else zero_row19(rm);
                    load_row19(plane+i*9, r0);
                    if (i<16) load_row19(plane+(i+1)*9, rp); else zero_row19(rp);
                    #pragma unroll
                    for (int j=0;j<17;j++)
                        acc[rr][j] += w[0]*rm[j]+w[1]*rm[j+1]+w[2]*rm[j+2]
                                    + w[3]*r0[j]+w[4]*r0[j+1]+w[5]*r0[j+2]
                                    + w[6]*rp[j]+w[7]*rp[j+1]+w[8]*rp[j+2];
                }
            }
        }
        #pragma unroll
        for (int rr=0;rr<5;rr++){
            if (rr < nr){
                const int i = base+rr;
                unsigned int* drow = c1 + o*153 + i*9;
                #pragma unroll
                for (int k=0;k<9;k++){
                    const float f0 = gelu_f(acc[rr][2*k]);
                    const float f1 = (k<8) ? gelu_f(acc[rr][2*k+1]) : 0.f;
                    drow[k] = pack2(f0,f1);
                }
            }
        }
    }
    __syncthreads();
    // ---- conv2 (64->64, 3x3) + gelu + separable gauss(17) reduction (no output buffer) ----
    {
        float acc[5][17];
        const float bo = st2_b[o];
        #pragma unroll
        for (int rr=0;rr<5;rr++)
            #pragma unroll
            for (int j=0;j<17;j++) acc[rr][j]=bo;
        for (int cc=0;cc<64;cc++){
            const float* wp = TR ? (W2 + (cc*64+o)*9) : (W2 + (o*64+cc)*9);
            float w[9];
            #pragma unroll
            for (int k=0;k<9;k++) w[k]=wp[k];
            const unsigned int* plane = c1 + cc*153;
            #pragma unroll
            for (int rr=0;rr<5;rr++){
                if (rr < nr){
                    const int i = base+rr;
                    float rm[19], r0[19], rp[19];
                    if (i>0)  load_row19(plane+(i-1)*9, rm); else zero_row19(rm);
                    load_row19(plane+i*9, r0);
                    if (i<16) load_row19(plane+(i+1)*9, rp); else zero_row19(rp);
                    #pragma unroll
                    for (int j=0;j<17;j++)
                        acc[rr][j] += w[0]*rm[j]+w[1]*rm[j+1]+w[2]*rm[j+2]
                                    + w[3]*r0[j]+w[4]*r0[j+1]+w[5]*r0[j+2]
                                    + w[6]*rp[j]+w[7]*rp[j+1]+w[8]*rp[j+2];
                }
            }
        }
        float ecol[17];
        #pragma unroll
        for (int j=0;j<17;j++){
            const float tj = -1.f + 0.125f*j;
            ecol[j] = expf(-3.125f*tj*tj);
        }
        float part = 0.f;
        #pragma unroll
        for (int rr=0;rr<5;rr++){
            if (rr < nr){
                const int i = base+rr;
                const float ti = -1.f + 0.125f*i;
                const float ei = expf(-3.125f*ti*ti);
                float rowa = 0.f;
                #pragma unroll
                for (int j=0;j<17;j++)
                    rowa += ecol[j]*gelu_f(acc[rr][j]);
                part += ei*rowa;
            }
        }
        redS[o*4+wid] = part;
    }
    __syncthreads();
    if (t < 64){
        float s = redS[t*4]+redS[t*4+1]+redS[t*4+2]+redS[t*4+3];
        float Sv = 0.f;
        #pragma unroll
        for (int j=0;j<17;j++){
            const float tj = -1.f + 0.125f*j;
            Sv += expf(-3.125f*tj*tj);
        }
        vec_out[n*192+128+t] = s/(Sv*Sv);
    }
}

// ---------------- Head MLP + sky transform (f32 outputs!) ----------------
__global__ __launch_bounds__(128) void head_kernel(
    const float* __restrict__ vec, const float* __restrict__ p2s,
    const float* __restrict__ h1_w, const float* __restrict__ h1_b,
    const float* __restrict__ h2_w, const float* __restrict__ h2_b,
    const float* __restrict__ h3_w, const float* __restrict__ h3_b,
    float* __restrict__ out, int N)
{
    __shared__ float v[192];
    __shared__ float x1[128];
    __shared__ float x2[128];
    const int n = blockIdx.x, t = threadIdx.x;
    v[t] = vec[n*192+t];
    if (t < 64) v[128+t] = vec[n*192+128+t];
    __syncthreads();
    {
        const float* w = h1_w + t*192;
        float a = h1_b[t];
        for (int k=0;k<192;k++) a += v[k]*w[k];
        x1[t] = gelu_f(a);
    }
    __syncthreads();
    {
        const float* w = h2_w + t*128;
        float a = h2_b[t];
        for (int k=0;k<128;k++) a += x1[k]*w[k];
        x2[t] = gelu_f(a);
    }
    __syncthreads();
    if (t == 0){
        float o3[3];
        #pragma unroll
        for (int j=0;j<3;j++){
            const float* w = h3_w + j*128;
            float a = h3_b[j];
            for (int k=0;k<128;k++) a += x2[k]*w[k];
            o3[j]=a;
        }
        const float dx=o3[0], dy=o3[1];
        float ls = o3[2];
        ls = ls < -6.f ? -6.f : (ls > 3.f ? 3.f : ls);
        const float s0 = p2s[n*4+0]*dx + p2s[n*4+1]*dy;
        const float s1 = p2s[n*4+2]*dx + p2s[n*4+3]*dy;
        const float conf = 1.0f/fmaxf(expf(ls), 1e-4f);
        out[2*n]   = s0;
        out[2*n+1] = s1;
        out[2*N+n] = dx;
        out[3*N+n] = dy;
        out[4*N+n] = ls;
        out[5*N+n] = conf;
    }
}

extern "C" void kernel_launch(void* const* d_in, const int* in_sizes, int n_in,
                              void* d_out, int out_size, void* d_ws, size_t ws_size,
                              hipStream_t stream)
{
    (void)n_in; (void)out_size;
    const float* bottleneck = (const float*)d_in[0];
    const float* vis        = (const float*)d_in[1];
    const float* pos        = (const float*)d_in[2];
    const float* p2s        = (const float*)d_in[3];
    const float* dw_w  = (const float*)d_in[8];
    const float* dw_b  = (const float*)d_in[9];
    const float* ln_g  = (const float*)d_in[10];
    const float* ln_b  = (const float*)d_in[11];
    const float* pw1_w = (const float*)d_in[12];
    const float* pw1_b = (const float*)d_in[13];
    const float* pw2_w = (const float*)d_in[14];
    const float* pw2_b = (const float*)d_in[15];
    const float* gam   = (const float*)d_in[16];
    const float* b1w   = (const float*)d_in[17];
    const float* b1b   = (const float*)d_in[18];
    const float* s1w   = (const float*)d_in[19];
    const float* s1b   = (const float*)d_in[20];
    const float* s2w   = (const float*)d_in[21];
    const float* s2b   = (const float*)d_in[22];
    const float* h1w   = (const float*)d_in[23];
    const float* h1b   = (const float*)d_in[24];
    const float* h2w   = (const float*)d_in[25];
    const float* h2b   = (const float*)d_in[26];
    const float* h3w   = (const float*)d_in[27];
    const float* h3b   = (const float*)d_in[28];

    const int N = in_sizes[2]/2;            // 4096
    float* vec = (float*)d_ws;              // [N][192] f32
    const size_t vec_bytes = (size_t)N*192*sizeof(float);

    // diagnostic + determinism: vec starts at zero
    hipMemsetAsync(d_ws, 0, vec_bytes, stream);

    const bool tr = ws_size >= vec_bytes + 2u*36864u*sizeof(float);
    float* Wt1 = (float*)((char*)d_ws + vec_bytes);
    float* Wt2 = Wt1 + 36864;

    bn_branch_kernel<<<N, 256, 0, stream>>>(bottleneck, pos, dw_w, dw_b, ln_g, ln_b,
                                            pw1_w, pw1_b, pw2_w, pw2_b, gam, b1w, b1b, vec);
    if (tr){
        transpose_w_kernel<<<288, 256, 0, stream>>>(s1w, s2w, Wt1, Wt2);
        stem_branch_kernel<true><<<N, 256, 0, stream>>>(vis, pos, Wt1, s1b, Wt2, s2b, vec);
    } else {
        stem_branch_kernel<false><<<N, 256, 0, stream>>>(vis, pos, s1w, s1b, s2w, s2b, vec);
    }
    head_kernel<<<N, 128, 0, stream>>>(vec, p2s, h1w, h1b, h2w, h2b, h3w, h3b,
                                       (float*)d_out, N);
}

// Round 4
// 2852.832 us; speedup vs baseline: 7.0976x; 7.0976x over previous
//
#include <hip/hip_runtime.h>
#include <hip/hip_bf16.h>

#define XSTR 28   // BN LDS row stride (floats), 16B aligned

typedef short short8 __attribute__((ext_vector_type(8)));
typedef float f32x4  __attribute__((ext_vector_type(4)));

__device__ __forceinline__ float gelu_f(float x){
    return 0.5f*x*(1.0f + erff(x*0.70710678118654752f));
}

__device__ __forceinline__ unsigned short f2bf(float f){
    unsigned int u = __float_as_uint(f);
    u += 0x7fffu + ((u>>16)&1u);
    return (unsigned short)(u>>16);
}
__device__ __forceinline__ unsigned int pack2(float a, float b){
    return (unsigned int)f2bf(a) | ((unsigned int)f2bf(b)<<16);
}

// acc[0..24] += row[0..24] * w   (row is 16B-aligned LDS, broadcast across wave)
__device__ __forceinline__ void fma_row25(const float* __restrict__ row, float w, float* __restrict__ acc){
    const float4* r4 = (const float4*)row;
    float4 a0=r4[0], a1=r4[1], a2=r4[2], a3=r4[3], a4=r4[4], a5=r4[5];
    float a6 = row[24];
    acc[0]+=a0.x*w;  acc[1]+=a0.y*w;  acc[2]+=a0.z*w;  acc[3]+=a0.w*w;
    acc[4]+=a1.x*w;  acc[5]+=a1.y*w;  acc[6]+=a1.z*w;  acc[7]+=a1.w*w;
    acc[8]+=a2.x*w;  acc[9]+=a2.y*w;  acc[10]+=a2.z*w; acc[11]+=a2.w*w;
    acc[12]+=a3.x*w; acc[13]+=a3.y*w; acc[14]+=a3.z*w; acc[15]+=a3.w*w;
    acc[16]+=a4.x*w; acc[17]+=a4.y*w; acc[18]+=a4.z*w; acc[19]+=a4.w*w;
    acc[20]+=a5.x*w; acc[21]+=a5.y*w; acc[22]+=a5.z*w; acc[23]+=a5.w*w;
    acc[24]+=a6*w;
}

// ---------------- BN (bottleneck) branch: one block per sample (unchanged, passing) ----------------
__global__ __launch_bounds__(256,2) void bn_branch_kernel(
    const float* __restrict__ bottleneck,   // [256,128,128]
    const float* __restrict__ pos,          // [N,2] vis coords
    const float* __restrict__ dw_w, const float* __restrict__ dw_b,
    const float* __restrict__ ln_g, const float* __restrict__ ln_b,
    const float* __restrict__ pw1_w, const float* __restrict__ pw1_b,
    const float* __restrict__ pw2_w, const float* __restrict__ pw2_b,
    const float* __restrict__ cn_gamma,
    const float* __restrict__ bn1x1_w, const float* __restrict__ bn1x1_b,
    float* __restrict__ vec_out)            // [N,192], writes [0:128]
{
    __shared__ float xln[256*XSTR];
    __shared__ float hbuf[256*XSTR];
    __shared__ float redA[200], redB[200];
    __shared__ float mu[25], rs[25];

    const int n = blockIdx.x;
    const int t = threadIdx.x;
    const int c = t;

    const float px = pos[2*n]*0.125f, py = pos[2*n+1]*0.125f;
    const float fpx = floorf(px), fpy = floorf(py);
    const int ix0 = (int)fpx - 2, iy0 = (int)fpy - 2;
    const float fx = px - fpx, fy = py - fpy;
    const float w00=(1.f-fy)*(1.f-fx), w01=(1.f-fy)*fx, w10=fy*(1.f-fx), w11=fy*fx;

    float wv[25];
    {
        const float* fm = bottleneck + c*16384;
        float P[6][6];
        #pragma unroll
        for (int r=0;r<6;r++){
            const int y = iy0+r;
            const bool yok = (y>=0)&&(y<128);
            const int yc = y<0?0:(y>127?127:y);
            #pragma unroll
            for (int s=0;s<6;s++){
                const int x = ix0+s;
                const bool ok = yok && (x>=0) && (x<128);
                const int xc = x<0?0:(x>127?127:x);
                P[r][s] = ok ? fm[yc*128+xc] : 0.f;
            }
        }
        #pragma unroll
        for (int a=0;a<5;a++)
        #pragma unroll
        for (int b=0;b<5;b++)
            wv[a*5+b] = w00*P[a][b]+w01*P[a][b+1]+w10*P[a+1][b]+w11*P[a+1][b+1];
    }
    {
        float wcr[49];
        const float* wc = dw_w + c*49;
        #pragma unroll
        for (int k=0;k<49;k++) wcr[k]=wc[k];
        const float bb = dw_b[c];
        #pragma unroll
        for (int i=0;i<5;i++){
            #pragma unroll
            for (int j=0;j<5;j++){
                float a = bb;
                #pragma unroll
                for (int u=0;u<7;u++){
                    const int y = i+u-3;
                    if (y<0||y>4) continue;
                    #pragma unroll
                    for (int v=0;v<7;v++){
                        const int x = j+v-3;
                        if (x<0||x>4) continue;
                        a += wv[y*5+x]*wcr[u*7+v];
                    }
                }
                xln[c*XSTR + i*5+j] = a;
            }
        }
    }
    __syncthreads();
    if (t < 200){
        const int p = t>>3, s = t&7;
        float a=0.f, b=0.f;
        for (int cc=s; cc<256; cc+=8){
            const float v = xln[cc*XSTR+p];
            a += v; b += v*v;
        }
        redA[t]=a; redB[t]=b;
    }
    __syncthreads();
    if (t < 25){
        float a=0.f, b=0.f;
        #pragma unroll
        for (int s=0;s<8;s++){ a+=redA[t*8+s]; b+=redB[t*8+s]; }
        const float m = a*(1.f/256.f);
        const float var = b*(1.f/256.f) - m*m;
        mu[t]=m; rs[t]=rsqrtf(var+1e-6f);
    }
    __syncthreads();
    {
        const float g = ln_g[c], bb = ln_b[c];
        #pragma unroll
        for (int p=0;p<25;p++)
            xln[c*XSTR+p] = (xln[c*XSTR+p]-mu[p])*rs[p]*g + bb;
    }
    __syncthreads();
    float acc2[25];
    #pragma unroll
    for (int p=0;p<25;p++) acc2[p]=0.f;
    for (int r=0;r<4;r++){
        const int o = r*256 + t;
        float h[25];
        {
            const float b1 = pw1_b[o];
            #pragma unroll
            for (int p=0;p<25;p++) h[p]=b1;
            const float* wr = pw1_w + o*256;
            for (int cc=0;cc<256;cc++)
                fma_row25(xln + cc*XSTR, wr[cc], h);
            #pragma unroll
            for (int p=0;p<25;p++) h[p]=gelu_f(h[p]);
        }
        __syncthreads();
        #pragma unroll
        for (int p=0;p<25;p++) hbuf[t*XSTR+p]=h[p];
        __syncthreads();
        {
            const float* w2 = pw2_w + t*1024 + r*256;
            for (int k=0;k<256;k++)
                fma_row25(hbuf + k*XSTR, w2[k], acc2);
        }
    }
    {
        const float gam = cn_gamma[c], b2 = pw2_b[c];
        #pragma unroll
        for (int p=0;p<25;p++)
            xln[c*XSTR+p] = wv[p] + gam*(acc2[p]+b2);
    }
    __syncthreads();
    if (t < 128){
        float acc[25];
        #pragma unroll
        for (int p=0;p<25;p++) acc[p]=0.f;
        const float* wr = bn1x1_w + t*256;
        for (int cc=0;cc<256;cc++)
            fma_row25(xln + cc*XSTR, wr[cc], acc);
        const float b = bn1x1_b[t];
        float e5[5];
        #pragma unroll
        for (int a=0;a<5;a++){
            const float ta = -1.f + 0.5f*a;
            e5[a] = expf(-3.125f*ta*ta);
        }
        const float Sv = e5[0]+e5[1]+e5[2]+e5[3]+e5[4];
        float res = 0.f;
        #pragma unroll
        for (int a=0;a<5;a++){
            float rowa = 0.f;
            #pragma unroll
            for (int bb=0;bb<5;bb++)
                rowa += e5[bb]*gelu_f(acc[a*5+bb]+b);
            res += e5[a]*rowa;
        }
        vec_out[n*192+t] = res/(Sv*Sv);
    }
}

// ---------------- Stem weight prepack: MFMA A-fragment layout, bf16 ----------------
// Apack[conv][k][s][w][lane][j] ; value = W[o=w*16+(lane&15)][c=s*32+(lane>>4)*8+j][k]
__global__ __launch_bounds__(256) void prepack_kernel(
    const float* __restrict__ W1, const float* __restrict__ W2,
    unsigned short* __restrict__ Ap)
{
    const int tid = blockIdx.x*256 + threadIdx.x;
    if (tid >= 9216) return;
    int r = tid;
    const int conv = r / 4608; r -= conv*4608;
    const int k = r / 512;     r -= k*512;
    const int s = r / 256;     r -= s*256;
    const int w = r / 64;
    const int l = r - w*64;
    const float* W = conv ? W2 : W1;
    const int o  = w*16 + (l & 15);
    const int c0 = s*32 + (l >> 4)*8;
    unsigned int v[4];
    #pragma unroll
    for (int jj=0; jj<4; jj++){
        const float f0 = W[o*576 + (c0+2*jj  )*9 + k];
        const float f1 = W[o*576 + (c0+2*jj+1)*9 + k];
        v[jj] = pack2(f0, f1);
    }
    uint4* dst = (uint4*)(Ap + (size_t)tid*8);
    *dst = make_uint4(v[0], v[1], v[2], v[3]);
}

// ---------------- Stem branch: MFMA version ----------------
// LDS layout: Xt[p][c] bf16, row = 128 B (64 ch), XOR-swizzled by ((p&7)<<4); row 305 = zeros.
#define STEM_CONV(SRC, AP, ACC)                                                     \
    for (int k=0;k<9;k++){                                                          \
        const int dy = k/3 - 1, dx = (k - (k/3)*3) - 1;                             \
        for (int s=0;s<2;s++){                                                      \
            const short8 av = (AP)[k*512 + s*256 + w*64 + lane];                    \
            const int cb = s*64 + h*16;                                             \
            _Pragma("unroll")                                                       \
            for (int nt=0; nt<19; nt++){                                            \
                const int p  = nt*16 + m;                                           \
                const int py = (p*241)>>12;                                         \
                const int px = p - py*17;                                           \
                const int y = py + dy, x = px + dx;                                 \
                const bool ok = ((unsigned)y < 17u) && ((unsigned)x < 17u);         \
                const int pp = ok ? (y*17 + x) : 305;                               \
                const int ad = pp*128 + (cb ^ ((pp&7)<<4));                         \
                const short8 bv = *(const short8*)((SRC) + ad);                     \
                ACC[nt] = __builtin_amdgcn_mfma_f32_16x16x32_bf16(av, bv, ACC[nt], 0, 0, 0); \
            }                                                                       \
        }                                                                           \
    }

__global__ __launch_bounds__(256,2) void stem_branch_kernel(
    const float* __restrict__ vis,   // [64,1024,1024]
    const float* __restrict__ pos,
    const short8* __restrict__ Ap1,  // prepacked conv1 weights (4608 frags)
    const float* __restrict__ st1_b,
    const float* __restrict__ st2_b,
    float* __restrict__ vec_out)     // [N,192], writes [128:192]
{
    __shared__ __align__(16) unsigned char sXt[306*128];  // 39168 B
    __shared__ __align__(16) unsigned char sC1[306*128];  // 39168 B
    __shared__ float redS[64];

    const int n = blockIdx.x;
    const int t = threadIdx.x;
    const int lane = t & 63;
    const int m = t & 15;          // N-index within tile (pixel)
    const int h = (t >> 4) & 3;    // K-chunk / D-row group
    const int w = t >> 6;          // wave = o-tile

    const float fpx0 = pos[2*n], fpy0 = pos[2*n+1];
    const float fpx = floorf(fpx0), fpy = floorf(fpy0);
    const int ix0 = (int)fpx - 8, iy0 = (int)fpy - 8;
    const float fx = fpx0-fpx, fy = fpy0-fpy;
    const float w00=(1.f-fy)*(1.f-fx), w01=(1.f-fy)*fx, w10=fy*(1.f-fx), w11=fy*fx;

    // zero row 305 of both buffers (the out-of-bounds target row)
    if (t < 32)      *(unsigned int*)(sXt + 305*128 + t*4) = 0u;
    else if (t < 64) *(unsigned int*)(sC1 + 305*128 + (t-32)*4) = 0u;

    // ---- blend 17x17 windows -> Xt[p][c] bf16 (positions are interior: loads in-bounds) ----
    for (int task = t; task < 64*17; task += 256){
        const int c  = task & 63;
        const int py = task >> 6;
        const float* r0 = vis + c*1048576 + (iy0+py)*1024 + ix0;
        float a[18], b[18];
        #pragma unroll
        for (int kk=0; kk<18; kk++){ a[kk]=r0[kk]; b[kk]=r0[1024+kk]; }
        #pragma unroll
        for (int px=0; px<17; px++){
            const float v = w00*a[px] + w01*a[px+1] + w10*b[px] + w11*b[px+1];
            const int p = py*17 + px;
            *(unsigned short*)(sXt + p*128 + ((2*c) ^ ((p&7)<<4))) = f2bf(v);
        }
    }
    __syncthreads();

    // ---- conv1: 9 shifted GEMMs via MFMA, acc over 19 N-tiles ----
    f32x4 acc[19];
    #pragma unroll
    for (int nt=0; nt<19; nt++) acc[nt] = 0.f;
    STEM_CONV(sXt, Ap1, acc)

    // epilogue: +bias, gelu, write c1t[p][o] bf16 (swizzled)
    {
        const int obase = w*16 + h*4;
        const float bo0 = st1_b[obase], bo1 = st1_b[obase+1];
        const float bo2 = st1_b[obase+2], bo3 = st1_b[obase+3];
        #pragma unroll
        for (int nt=0; nt<19; nt++){
            const int p = nt*16 + m;
            if (p < 304){
                const unsigned r01 = pack2(gelu_f(acc[nt].x+bo0), gelu_f(acc[nt].y+bo1));
                const unsigned r23 = pack2(gelu_f(acc[nt].z+bo2), gelu_f(acc[nt].w+bo3));
                const int ad = p*128 + ((2*obase) ^ ((p&7)<<4));
                *(uint2*)(sC1 + ad) = make_uint2(r01, r23);
            }
        }
    }
    __syncthreads();

    // ---- conv2 + gelu + gauss reduction (no output buffer) ----
    const short8* Ap2 = Ap1 + 4608;
    #pragma unroll
    for (int nt=0; nt<19; nt++) acc[nt] = 0.f;
    STEM_CONV(sC1, Ap2, acc)

    {
        const int obase = w*16 + h*4;
        const float bo0 = st2_b[obase], bo1 = st2_b[obase+1];
        const float bo2 = st2_b[obase+2], bo3 = st2_b[obase+3];
        float s0=0.f, s1=0.f, s2=0.f, s3=0.f;
        #pragma unroll
        for (int nt=0; nt<19; nt++){
            const int p = nt*16 + m;
            if (p < 289){
                const int py = (p*241)>>12;
                const int px = p - py*17;
                const float ty = -1.f + 0.125f*py;
                const float tx = -1.f + 0.125f*px;
                const float g = expf(-3.125f*(ty*ty + tx*tx));
                s0 += g*gelu_f(acc[nt].x+bo0);
                s1 += g*gelu_f(acc[nt].y+bo1);
                s2 += g*gelu_f(acc[nt].z+bo2);
                s3 += g*gelu_f(acc[nt].w+bo3);
            }
        }
        #pragma unroll
        for (int off=1; off<16; off<<=1){
            s0 += __shfl_xor(s0, off);
            s1 += __shfl_xor(s1, off);
            s2 += __shfl_xor(s2, off);
            s3 += __shfl_xor(s3, off);
        }
        if (m == 0){
            redS[obase]   = s0;
            redS[obase+1] = s1;
            redS[obase+2] = s2;
            redS[obase+3] = s3;
        }
    }
    __syncthreads();
    if (t < 64){
        float Sv = 0.f;
        #pragma unroll
        for (int j=0;j<17;j++){
            const float tj = -1.f + 0.125f*j;
            Sv += expf(-3.125f*tj*tj);
        }
        vec_out[n*192+128+t] = redS[t] / (Sv*Sv);
    }
}

// ---------------- Head MLP + sky transform (f32 outputs) ----------------
__global__ __launch_bounds__(128) void head_kernel(
    const float* __restrict__ vec, const float* __restrict__ p2s,
    const float* __restrict__ h1_w, const float* __restrict__ h1_b,
    const float* __restrict__ h2_w, const float* __restrict__ h2_b,
    const float* __restrict__ h3_w, const float* __restrict__ h3_b,
    float* __restrict__ out, int N)
{
    __shared__ float v[192];
    __shared__ float x1[128];
    __shared__ float x2[128];
    const int n = blockIdx.x, t = threadIdx.x;
    v[t] = vec[n*192+t];
    if (t < 64) v[128+t] = vec[n*192+128+t];
    __syncthreads();
    {
        const float* w = h1_w + t*192;
        float a = h1_b[t];
        for (int k=0;k<192;k++) a += v[k]*w[k];
        x1[t] = gelu_f(a);
    }
    __syncthreads();
    {
        const float* w = h2_w + t*128;
        float a = h2_b[t];
        for (int k=0;k<128;k++) a += x1[k]*w[k];
        x2[t] = gelu_f(a);
    }
    __syncthreads();
    if (t == 0){
        float o3[3];
        #pragma unroll
        for (int j=0;j<3;j++){
            const float* w = h3_w + j*128;
            float a = h3_b[j];
            for (int k=0;k<128;k++) a += x2[k]*w[k];
            o3[j]=a;
        }
        const float dx=o3[0], dy=o3[1];
        float ls = o3[2];
        ls = ls < -6.f ? -6.f : (ls > 3.f ? 3.f : ls);
        const float s0 = p2s[n*4+0]*dx + p2s[n*4+1]*dy;
        const float s1 = p2s[n*4+2]*dx + p2s[n*4+3]*dy;
        const float conf = 1.0f/fmaxf(expf(ls), 1e-4f);
        out[2*n]   = s0;
        out[2*n+1] = s1;
        out[2*N+n] = dx;
        out[3*N+n] = dy;
        out[4*N+n] = ls;
        out[5*N+n] = conf;
    }
}

extern "C" void kernel_launch(void* const* d_in, const int* in_sizes, int n_in,
                              void* d_out, int out_size, void* d_ws, size_t ws_size,
                              hipStream_t stream)
{
    (void)n_in; (void)out_size; (void)ws_size;
    const float* bottleneck = (const float*)d_in[0];
    const float* vis        = (const float*)d_in[1];
    const float* pos        = (const float*)d_in[2];
    const float* p2s        = (const float*)d_in[3];
    const float* dw_w  = (const float*)d_in[8];
    const float* dw_b  = (const float*)d_in[9];
    const float* ln_g  = (const float*)d_in[10];
    const float* ln_b  = (const float*)d_in[11];
    const float* pw1_w = (const float*)d_in[12];
    const float* pw1_b = (const float*)d_in[13];
    const float* pw2_w = (const float*)d_in[14];
    const float* pw2_b = (const float*)d_in[15];
    const float* gam   = (const float*)d_in[16];
    const float* b1w   = (const float*)d_in[17];
    const float* b1b   = (const float*)d_in[18];
    const float* s1w   = (const float*)d_in[19];
    const float* s1b   = (const float*)d_in[20];
    const float* s2w   = (const float*)d_in[21];
    const float* s2b   = (const float*)d_in[22];
    const float* h1w   = (const float*)d_in[23];
    const float* h1b   = (const float*)d_in[24];
    const float* h2w   = (const float*)d_in[25];
    const float* h2b   = (const float*)d_in[26];
    const float* h3w   = (const float*)d_in[27];
    const float* h3b   = (const float*)d_in[28];

    const int N = in_sizes[2]/2;            // 4096
    float* vec = (float*)d_ws;              // [N][192] f32
    const size_t vec_bytes = (size_t)N*192*sizeof(float);
    unsigned short* Apack = (unsigned short*)((char*)d_ws + vec_bytes);  // 9216*8 bf16 = 147456 B

    hipMemsetAsync(d_ws, 0, vec_bytes, stream);

    prepack_kernel<<<36, 256, 0, stream>>>(s1w, s2w, Apack);
    bn_branch_kernel<<<N, 256, 0, stream>>>(bottleneck, pos, dw_w, dw_b, ln_g, ln_b,
                                            pw1_w, pw1_b, pw2_w, pw2_b, gam, b1w, b1b, vec);
    stem_branch_kernel<<<N, 256, 0, stream>>>(vis, pos, (const short8*)Apack, s1b, s2b, vec);
    head_kernel<<<N, 128, 0, stream>>>(vec, p2s, h1w, h1b, h2w, h2b, h3w, h3b,
                                       (float*)d_out, N);
}

// Round 6
// 1148.675 us; speedup vs baseline: 17.6275x; 2.4836x over previous
//
#include <hip/hip_runtime.h>
#include <hip/hip_bf16.h>

#define XSTR 28   // legacy BN VALU kernel stride

typedef short short8 __attribute__((ext_vector_type(8)));
typedef float f32x4  __attribute__((ext_vector_type(4)));

__device__ __forceinline__ float gelu_f(float x){
    return 0.5f*x*(1.0f + erff(x*0.70710678118654752f));
}
__device__ __forceinline__ unsigned short f2bf(float f){
    unsigned int u = __float_as_uint(f);
    u += 0x7fffu + ((u>>16)&1u);
    return (unsigned short)(u>>16);
}
__device__ __forceinline__ unsigned int pack2(float a, float b){
    return (unsigned int)f2bf(a) | ((unsigned int)f2bf(b)<<16);
}
__device__ __forceinline__ float bf_lo(unsigned int u){ return __uint_as_float(u<<16); }
__device__ __forceinline__ float bf_hi(unsigned int u){ return __uint_as_float(u & 0xffff0000u); }

__device__ __forceinline__ void fma_row25(const float* __restrict__ row, float w, float* __restrict__ acc){
    const float4* r4 = (const float4*)row;
    float4 a0=r4[0], a1=r4[1], a2=r4[2], a3=r4[3], a4=r4[4], a5=r4[5];
    float a6 = row[24];
    acc[0]+=a0.x*w;  acc[1]+=a0.y*w;  acc[2]+=a0.z*w;  acc[3]+=a0.w*w;
    acc[4]+=a1.x*w;  acc[5]+=a1.y*w;  acc[6]+=a1.z*w;  acc[7]+=a1.w*w;
    acc[8]+=a2.x*w;  acc[9]+=a2.y*w;  acc[10]+=a2.z*w; acc[11]+=a2.w*w;
    acc[12]+=a3.x*w; acc[13]+=a3.y*w; acc[14]+=a3.z*w; acc[15]+=a3.w*w;
    acc[16]+=a4.x*w; acc[17]+=a4.y*w; acc[18]+=a4.z*w; acc[19]+=a4.w*w;
    acc[20]+=a5.x*w; acc[21]+=a5.y*w; acc[22]+=a5.z*w; acc[23]+=a5.w*w;
    acc[24]+=a6*w;
}

// ================= BN branch, MFMA version =================
// LDS: Xb/tmp alias (26.6KB), Rb 16KB, Hc 8KB. [p][c] bf16 rows, XOR swizzle ((p&7)<<4).
__global__ __launch_bounds__(512,4) void bn_branch_mfma(
    const float* __restrict__ bottleneck, const float* __restrict__ pos,
    const float* __restrict__ dw_w, const float* __restrict__ dw_b,
    const float* __restrict__ ln_g, const float* __restrict__ ln_b,
    const float* __restrict__ pw1_b, const float* __restrict__ pw2_b,
    const float* __restrict__ cn_gamma, const float* __restrict__ bn1x1_b,
    const short8* __restrict__ P1v, const short8* __restrict__ P2v,
    const short8* __restrict__ Pbv,
    float* __restrict__ vec_out)
{
    __shared__ __align__(16) float SBf[256*26];            // tmp f32 -> (first 16KB) Xb bf16
    __shared__ __align__(16) unsigned char Rb[32*512];     // residual bf16 [32p][256c]
    __shared__ __align__(16) unsigned char Hc[32*256];     // h-chunk bf16 [32p][128k]
    __shared__ float redA[200], redB[200], muS[25], rsS[25];
    unsigned char* Xb = (unsigned char*)SBf;

    const int n = blockIdx.x, t = threadIdx.x;
    const int lane = t & 63, w = t >> 6;
    const int mcol = lane & 15, h4 = lane >> 4;

    float xdw[25];
    if (t < 256){
        const int c = t;
        const float px = pos[2*n]*0.125f, py = pos[2*n+1]*0.125f;
        const float fpx = floorf(px), fpy = floorf(py);
        const int ix0 = (int)fpx - 2, iy0 = (int)fpy - 2;
        const float fx = px - fpx, fy = py - fpy;
        const float w00=(1.f-fy)*(1.f-fx), w01=(1.f-fy)*fx, w10=fy*(1.f-fx), w11=fy*fx;
        float wv[25];
        {
            const float* fm = bottleneck + c*16384;
            float P[6][6];
            #pragma unroll
            for (int r=0;r<6;r++){
                const int y = iy0+r;
                const bool yok = (y>=0)&&(y<128);
                const int yc = y<0?0:(y>127?127:y);
                #pragma unroll
                for (int s=0;s<6;s++){
                    const int x = ix0+s;
                    const bool ok = yok && (x>=0) && (x<128);
                    const int xc = x<0?0:(x>127?127:x);
                    P[r][s] = ok ? fm[yc*128+xc] : 0.f;
                }
            }
            #pragma unroll
            for (int a=0;a<5;a++)
            #pragma unroll
            for (int b=0;b<5;b++)
                wv[a*5+b] = w00*P[a][b]+w01*P[a][b+1]+w10*P[a+1][b]+w11*P[a+1][b+1];
        }
        // residual -> Rb bf16
        #pragma unroll
        for (int p=0;p<25;p++)
            *(unsigned short*)(Rb + p*512 + ((2*c) ^ ((p&7)<<4))) = f2bf(wv[p]);
        // depthwise 7x7
        {
            float wcr[49];
            const float* wc = dw_w + c*49;
            #pragma unroll
            for (int k=0;k<49;k++) wcr[k]=wc[k];
            const float bb = dw_b[c];
            #pragma unroll
            for (int i=0;i<5;i++){
                #pragma unroll
                for (int j=0;j<5;j++){
                    float a = bb;
                    #pragma unroll
                    for (int u=0;u<7;u++){
                        const int y = i+u-3;
                        if (y<0||y>4) continue;
                        #pragma unroll
                        for (int v=0;v<7;v++){
                            const int x = j+v-3;
                            if (x<0||x>4) continue;
                            a += wv[y*5+x]*wcr[u*7+v];
                        }
                    }
                    xdw[i*5+j] = a;
                }
            }
        }
        #pragma unroll
        for (int p=0;p<25;p++) SBf[c*26+p] = xdw[p];
    } else {
        const int q = t - 256;
        for (int z=q; z<896; z+=256) ((unsigned int*)(Rb + 12800))[z] = 0u;
    }
    __syncthreads();
    if (t < 200){
        const int p = t>>3, s = t&7;
        float a=0.f, b=0.f;
        for (int cc=s; cc<256; cc+=8){
            const float v = SBf[cc*26+p];
            a += v; b += v*v;
        }
        redA[t]=a; redB[t]=b;
    }
    __syncthreads();
    if (t < 25){
        float a=0.f, b=0.f;
        #pragma unroll
        for (int s=0;s<8;s++){ a+=redA[t*8+s]; b+=redB[t*8+s]; }
        const float m = a*(1.f/256.f);
        const float var = b*(1.f/256.f) - m*m;
        muS[t]=m; rsS[t]=rsqrtf(var+1e-6f);
    }
    __syncthreads();
    if (t < 256){
        const int c = t;
        const float g = ln_g[c], bb = ln_b[c];
        #pragma unroll
        for (int p=0;p<25;p++)
            *(unsigned short*)(Xb + p*512 + ((2*c) ^ ((p&7)<<4))) =
                f2bf((xdw[p]-muS[p])*rsS[p]*g + bb);
    } else {
        const int q = t - 256;
        for (int z=q; z<896; z+=256) ((unsigned int*)(Xb + 12800))[z] = 0u;
    }
    __syncthreads();

    // ---- chunked pw1 -> pw2 ----
    f32x4 acc2[2][2];
    #pragma unroll
    for (int ml=0;ml<2;ml++){ acc2[ml][0]=0.f; acc2[ml][1]=0.f; }

    for (int ch=0; ch<8; ++ch){
        const int mt = ch*8 + w;                 // pw1 M-tile
        f32x4 a1[2]; a1[0]=0.f; a1[1]=0.f;
        #pragma unroll
        for (int kk=0; kk<8; ++kk){
            const short8 av = P1v[((mt<<3)+kk)*64 + lane];
            #pragma unroll
            for (int nt=0; nt<2; ++nt){
                const int p = nt*16 + mcol;
                const int ad = p*512 + ((kk*64 + h4*16) ^ ((p&7)<<4));
                const short8 bv = *(const short8*)(Xb + ad);
                a1[nt] = __builtin_amdgcn_mfma_f32_16x16x32_bf16(av, bv, a1[nt], 0,0,0);
            }
        }
        {
            const float4 b1v = *(const float4*)(pw1_b + mt*16 + h4*4);
            #pragma unroll
            for (int nt=0; nt<2; ++nt){
                const int p = nt*16 + mcol;
                const float g0 = gelu_f(a1[nt].x + b1v.x);
                const float g1 = gelu_f(a1[nt].y + b1v.y);
                const float g2 = gelu_f(a1[nt].z + b1v.z);
                const float g3 = gelu_f(a1[nt].w + b1v.w);
                const int ad = p*256 + ((w*32 + h4*8) ^ ((p&7)<<4));
                *(uint2*)(Hc + ad) = make_uint2(pack2(g0,g1), pack2(g2,g3));
            }
        }
        __syncthreads();
        #pragma unroll
        for (int ml=0; ml<2; ++ml){
            const int mtc = w*2 + ml;
            #pragma unroll
            for (int kk2=0; kk2<4; ++kk2){
                const short8 av = P2v[(mtc*32 + (ch*4 + kk2))*64 + lane];
                #pragma unroll
                for (int nt=0; nt<2; ++nt){
                    const int p = nt*16 + mcol;
                    const int ad = p*256 + ((kk2*64 + h4*16) ^ ((p&7)<<4));
                    const short8 bv = *(const short8*)(Hc + ad);
                    acc2[ml][nt] = __builtin_amdgcn_mfma_f32_16x16x32_bf16(av, bv, acc2[ml][nt], 0,0,0);
                }
            }
        }
        __syncthreads();
    }

    // ---- pw2 epilogue: residual + gamma -> Xb (final features) ----
    #pragma unroll
    for (int ml=0; ml<2; ++ml){
        const int mtc = w*2 + ml;
        const int c0 = mtc*16 + h4*4;
        const float4 gm = *(const float4*)(cn_gamma + c0);
        const float4 b2 = *(const float4*)(pw2_b + c0);
        #pragma unroll
        for (int nt=0; nt<2; ++nt){
            const int p = nt*16 + mcol;
            const int ad = p*512 + ((c0*2) ^ ((p&7)<<4));
            const uint2 rb = *(const uint2*)(Rb + ad);
            const float f0 = bf_lo(rb.x) + gm.x*(acc2[ml][nt].x + b2.x);
            const float f1 = bf_hi(rb.x) + gm.y*(acc2[ml][nt].y + b2.y);
            const float f2 = bf_lo(rb.y) + gm.z*(acc2[ml][nt].z + b2.z);
            const float f3 = bf_hi(rb.y) + gm.w*(acc2[ml][nt].w + b2.w);
            *(uint2*)(Xb + ad) = make_uint2(pack2(f0,f1), pack2(f2,f3));
        }
    }
    __syncthreads();

    // ---- bn1x1 + gelu + gauss(5) ----
    {
        f32x4 a3[2]; a3[0]=0.f; a3[1]=0.f;
        #pragma unroll
        for (int kk=0; kk<8; ++kk){
            const short8 av = Pbv[((w<<3)+kk)*64 + lane];
            #pragma unroll
            for (int nt=0; nt<2; ++nt){
                const int p = nt*16 + mcol;
                const int ad = p*512 + ((kk*64 + h4*16) ^ ((p&7)<<4));
                const short8 bv = *(const short8*)(Xb + ad);
                a3[nt] = __builtin_amdgcn_mfma_f32_16x16x32_bf16(av, bv, a3[nt], 0,0,0);
            }
        }
        const float4 bb = *(const float4*)(bn1x1_b + w*16 + h4*4);
        float e5[5];
        #pragma unroll
        for (int a=0;a<5;a++){
            const float ta = -1.f + 0.5f*a;
            e5[a] = expf(-3.125f*ta*ta);
        }
        const float Sv = e5[0]+e5[1]+e5[2]+e5[3]+e5[4];
        const float invS = 1.0f/(Sv*Sv);
        float s0=0.f, s1=0.f, s2=0.f, s3=0.f;
        #pragma unroll
        for (int nt=0; nt<2; ++nt){
            const int p = nt*16 + mcol;
            if (p < 25){
                const int pa = p/5, pb = p - pa*5;
                const float g = e5[pa]*e5[pb];
                s0 += g*gelu_f(a3[nt].x + bb.x);
                s1 += g*gelu_f(a3[nt].y + bb.y);
                s2 += g*gelu_f(a3[nt].z + bb.z);
                s3 += g*gelu_f(a3[nt].w + bb.w);
            }
        }
        #pragma unroll
        for (int off=1; off<16; off<<=1){
            s0 += __shfl_xor(s0, off);
            s1 += __shfl_xor(s1, off);
            s2 += __shfl_xor(s2, off);
            s3 += __shfl_xor(s3, off);
        }
        if (mcol == 0){
            const int o = w*16 + h4*4;
            vec_out[n*192 + o + 0] = s0*invS;
            vec_out[n*192 + o + 1] = s1*invS;
            vec_out[n*192 + o + 2] = s2*invS;
            vec_out[n*192 + o + 3] = s3*invS;
        }
    }
}

// ---- bn weight prepack: f32 -> bf16 MFMA A-fragments ----
// P1: pw1 [1024][256] -> 512 frags (32768 lanes)
// P2: pw2 [256][1024] -> 512 frags (32768 lanes)   [FIXED: was 1024 frags, OOB + Pb overwrite race]
// Pb: bn1x1 [128][256] -> 64 frags (4096 lanes)
__global__ __launch_bounds__(256) void prepack_bn_kernel(
    const float* __restrict__ W1, const float* __restrict__ W2, const float* __restrict__ Wb,
    unsigned short* __restrict__ P1, unsigned short* __restrict__ P2, unsigned short* __restrict__ Pb)
{
    const int tid = blockIdx.x*256 + threadIdx.x;
    const float* src; unsigned short* dst; int row, col, stride, idx;
    if (tid < 32768){
        idx = tid;
        const int frag = idx>>6, l = idx&63;
        row = (frag>>3)*16 + (l&15); col = (frag&7)*32 + (l>>4)*8; stride = 256;
        src = W1; dst = P1;
    } else if (tid < 65536){
        idx = tid - 32768;
        const int frag = idx>>6, l = idx&63;
        row = (frag>>5)*16 + (l&15); col = (frag&31)*32 + (l>>4)*8; stride = 1024;
        src = W2; dst = P2;
    } else if (tid < 69632){
        idx = tid - 65536;
        const int frag = idx>>6, l = idx&63;
        row = (frag>>3)*16 + (l&15); col = (frag&7)*32 + (l>>4)*8; stride = 256;
        src = Wb; dst = Pb;
    } else return;
    const float* s = src + row*stride + col;
    unsigned int v[4];
    #pragma unroll
    for (int j=0;j<4;j++) v[j] = pack2(s[2*j], s[2*j+1]);
    *(uint4*)(dst + (size_t)idx*8) = make_uint4(v[0],v[1],v[2],v[3]);
}

// ================= BN branch, VALU fallback (round-4 proven) =================
__global__ __launch_bounds__(256,2) void bn_branch_valu(
    const float* __restrict__ bottleneck, const float* __restrict__ pos,
    const float* __restrict__ dw_w, const float* __restrict__ dw_b,
    const float* __restrict__ ln_g, const float* __restrict__ ln_b,
    const float* __restrict__ pw1_w, const float* __restrict__ pw1_b,
    const float* __restrict__ pw2_w, const float* __restrict__ pw2_b,
    const float* __restrict__ cn_gamma,
    const float* __restrict__ bn1x1_w, const float* __restrict__ bn1x1_b,
    float* __restrict__ vec_out)
{
    __shared__ float xln[256*XSTR];
    __shared__ float hbuf[256*XSTR];
    __shared__ float redA[200], redB[200];
    __shared__ float mu[25], rs[25];

    const int n = blockIdx.x;
    const int t = threadIdx.x;
    const int c = t;

    const float px = pos[2*n]*0.125f, py = pos[2*n+1]*0.125f;
    const float fpx = floorf(px), fpy = floorf(py);
    const int ix0 = (int)fpx - 2, iy0 = (int)fpy - 2;
    const float fx = px - fpx, fy = py - fpy;
    const float w00=(1.f-fy)*(1.f-fx), w01=(1.f-fy)*fx, w10=fy*(1.f-fx), w11=fy*fx;

    float wv[25];
    {
        const float* fm = bottleneck + c*16384;
        float P[6][6];
        #pragma unroll
        for (int r=0;r<6;r++){
            const int y = iy0+r;
            const bool yok = (y>=0)&&(y<128);
            const int yc = y<0?0:(y>127?127:y);
            #pragma unroll
            for (int s=0;s<6;s++){
                const int x = ix0+s;
                const bool ok = yok && (x>=0) && (x<128);
                const int xc = x<0?0:(x>127?127:x);
                P[r][s] = ok ? fm[yc*128+xc] : 0.f;
            }
        }
        #pragma unroll
        for (int a=0;a<5;a++)
        #pragma unroll
        for (int b=0;b<5;b++)
            wv[a*5+b] = w00*P[a][b]+w01*P[a][b+1]+w10*P[a+1][b]+w11*P[a+1][b+1];
    }
    {
        float wcr[49];
        const float* wc = dw_w + c*49;
        #pragma unroll
        for (int k=0;k<49;k++) wcr[k]=wc[k];
        const float bb = dw_b[c];
        #pragma unroll
        for (int i=0;i<5;i++){
            #pragma unroll
            for (int j=0;j<5;j++){
                float a = bb;
                #pragma unroll
                for (int u=0;u<7;u++){
                    const int y = i+u-3;
                    if (y<0||y>4) continue;
                    #pragma unroll
                    for (int v=0;v<7;v++){
                        const int x = j+v-3;
                        if (x<0||x>4) continue;
                        a += wv[y*5+x]*wcr[u*7+v];
                    }
                }
                xln[c*XSTR + i*5+j] = a;
            }
        }
    }
    __syncthreads();
    if (t < 200){
        const int p = t>>3, s = t&7;
        float a=0.f, b=0.f;
        for (int cc=s; cc<256; cc+=8){
            const float v = xln[cc*XSTR+p];
            a += v; b += v*v;
        }
        redA[t]=a; redB[t]=b;
    }
    __syncthreads();
    if (t < 25){
        float a=0.f, b=0.f;
        #pragma unroll
        for (int s=0;s<8;s++){ a+=redA[t*8+s]; b+=redB[t*8+s]; }
        const float m = a*(1.f/256.f);
        const float var = b*(1.f/256.f) - m*m;
        mu[t]=m; rs[t]=rsqrtf(var+1e-6f);
    }
    __syncthreads();
    {
        const float g = ln_g[c], bb = ln_b[c];
        #pragma unroll
        for (int p=0;p<25;p++)
            xln[c*XSTR+p] = (xln[c*XSTR+p]-mu[p])*rs[p]*g + bb;
    }
    __syncthreads();
    float acc2[25];
    #pragma unroll
    for (int p=0;p<25;p++) acc2[p]=0.f;
    for (int r=0;r<4;r++){
        const int o = r*256 + t;
        float h[25];
        {
            const float b1 = pw1_b[o];
            #pragma unroll
            for (int p=0;p<25;p++) h[p]=b1;
            const float* wr = pw1_w + o*256;
            for (int cc=0;cc<256;cc++)
                fma_row25(xln + cc*XSTR, wr[cc], h);
            #pragma unroll
            for (int p=0;p<25;p++) h[p]=gelu_f(h[p]);
        }
        __syncthreads();
        #pragma unroll
        for (int p=0;p<25;p++) hbuf[t*XSTR+p]=h[p];
        __syncthreads();
        {
            const float* w2 = pw2_w + t*1024 + r*256;
            for (int k=0;k<256;k++)
                fma_row25(hbuf + k*XSTR, w2[k], acc2);
        }
    }
    {
        const float gam = cn_gamma[c], b2 = pw2_b[c];
        #pragma unroll
        for (int p=0;p<25;p++)
            xln[c*XSTR+p] = wv[p] + gam*(acc2[p]+b2);
    }
    __syncthreads();
    if (t < 128){
        float acc[25];
        #pragma unroll
        for (int p=0;p<25;p++) acc[p]=0.f;
        const float* wr = bn1x1_w + t*256;
        for (int cc=0;cc<256;cc++)
            fma_row25(xln + cc*XSTR, wr[cc], acc);
        const float b = bn1x1_b[t];
        float e5[5];
        #pragma unroll
        for (int a=0;a<5;a++){
            const float ta = -1.f + 0.5f*a;
            e5[a] = expf(-3.125f*ta*ta);
        }
        const float Sv = e5[0]+e5[1]+e5[2]+e5[3]+e5[4];
        float res = 0.f;
        #pragma unroll
        for (int a=0;a<5;a++){
            float rowa = 0.f;
            #pragma unroll
            for (int bb=0;bb<5;bb++)
                rowa += e5[bb]*gelu_f(acc[a*5+bb]+b);
            res += e5[a]*rowa;
        }
        vec_out[n*192+t] = res/(Sv*Sv);
    }
}

// ---------------- Stem weight prepack (unchanged, proven) ----------------
__global__ __launch_bounds__(256) void prepack_kernel(
    const float* __restrict__ W1, const float* __restrict__ W2,
    unsigned short* __restrict__ Ap)
{
    const int tid = blockIdx.x*256 + threadIdx.x;
    if (tid >= 9216) return;
    int r = tid;
    const int conv = r / 4608; r -= conv*4608;
    const int k = r / 512;     r -= k*512;
    const int s = r / 256;     r -= s*256;
    const int w = r / 64;
    const int l = r - w*64;
    const float* W = conv ? W2 : W1;
    const int o  = w*16 + (l & 15);
    const int c0 = s*32 + (l >> 4)*8;
    unsigned int v[4];
    #pragma unroll
    for (int jj=0; jj<4; jj++){
        const float f0 = W[o*576 + (c0+2*jj  )*9 + k];
        const float f1 = W[o*576 + (c0+2*jj+1)*9 + k];
        v[jj] = pack2(f0, f1);
    }
    uint4* dst = (uint4*)(Ap + (size_t)tid*8);
    *dst = make_uint4(v[0], v[1], v[2], v[3]);
}

// ---------------- Stem branch: MFMA version (unchanged, proven) ----------------
#define STEM_CONV(SRC, AP, ACC)                                                     \
    for (int k=0;k<9;k++){                                                          \
        const int dy = k/3 - 1, dx = (k - (k/3)*3) - 1;                             \
        for (int s=0;s<2;s++){                                                      \
            const short8 av = (AP)[k*512 + s*256 + w*64 + lane];                    \
            const int cb = s*64 + h*16;                                             \
            _Pragma("unroll")                                                       \
            for (int nt=0; nt<19; nt++){                                            \
                const int p  = nt*16 + m;                                           \
                const int py = (p*241)>>12;                                         \
                const int px = p - py*17;                                           \
                const int y = py + dy, x = px + dx;                                 \
                const bool ok = ((unsigned)y < 17u) && ((unsigned)x < 17u);         \
                const int pp = ok ? (y*17 + x) : 305;                               \
                const int ad = pp*128 + (cb ^ ((pp&7)<<4));                         \
                const short8 bv = *(const short8*)((SRC) + ad);                     \
                ACC[nt] = __builtin_amdgcn_mfma_f32_16x16x32_bf16(av, bv, ACC[nt], 0, 0, 0); \
            }                                                                       \
        }                                                                           \
    }

__global__ __launch_bounds__(256,2) void stem_branch_kernel(
    const float* __restrict__ vis,
    const float* __restrict__ pos,
    const short8* __restrict__ Ap1,
    const float* __restrict__ st1_b,
    const float* __restrict__ st2_b,
    float* __restrict__ vec_out)
{
    __shared__ __align__(16) unsigned char sXt[306*128];
    __shared__ __align__(16) unsigned char sC1[306*128];
    __shared__ float redS[64];

    const int n = blockIdx.x;
    const int t = threadIdx.x;
    const int lane = t & 63;
    const int m = t & 15;
    const int h = (t >> 4) & 3;
    const int w = t >> 6;

    const float fpx0 = pos[2*n], fpy0 = pos[2*n+1];
    const float fpx = floorf(fpx0), fpy = floorf(fpy0);
    const int ix0 = (int)fpx - 8, iy0 = (int)fpy - 8;
    const float fx = fpx0-fpx, fy = fpy0-fpy;
    const float w00=(1.f-fy)*(1.f-fx), w01=(1.f-fy)*fx, w10=fy*(1.f-fx), w11=fy*fx;

    if (t < 32)      *(unsigned int*)(sXt + 305*128 + t*4) = 0u;
    else if (t < 64) *(unsigned int*)(sC1 + 305*128 + (t-32)*4) = 0u;

    for (int task = t; task < 64*17; task += 256){
        const int c  = task & 63;
        const int py = task >> 6;
        const float* r0 = vis + c*1048576 + (iy0+py)*1024 + ix0;
        float a[18], b[18];
        #pragma unroll
        for (int kk=0; kk<18; kk++){ a[kk]=r0[kk]; b[kk]=r0[1024+kk]; }
        #pragma unroll
        for (int px=0; px<17; px++){
            const float v = w00*a[px] + w01*a[px+1] + w10*b[px] + w11*b[px+1];
            const int p = py*17 + px;
            *(unsigned short*)(sXt + p*128 + ((2*c) ^ ((p&7)<<4))) = f2bf(v);
        }
    }
    __syncthreads();

    f32x4 acc[19];
    #pragma unroll
    for (int nt=0; nt<19; nt++) acc[nt] = 0.f;
    STEM_CONV(sXt, Ap1, acc)

    {
        const int obase = w*16 + h*4;
        const float bo0 = st1_b[obase], bo1 = st1_b[obase+1];
        const float bo2 = st1_b[obase+2], bo3 = st1_b[obase+3];
        #pragma unroll
        for (int nt=0; nt<19; nt++){
            const int p = nt*16 + m;
            if (p < 304){
                const unsigned r01 = pack2(gelu_f(acc[nt].x+bo0), gelu_f(acc[nt].y+bo1));
                const unsigned r23 = pack2(gelu_f(acc[nt].z+bo2), gelu_f(acc[nt].w+bo3));
                const int ad = p*128 + ((2*obase) ^ ((p&7)<<4));
                *(uint2*)(sC1 + ad) = make_uint2(r01, r23);
            }
        }
    }
    __syncthreads();

    const short8* Ap2 = Ap1 + 4608;
    #pragma unroll
    for (int nt=0; nt<19; nt++) acc[nt] = 0.f;
    STEM_CONV(sC1, Ap2, acc)

    {
        const int obase = w*16 + h*4;
        const float bo0 = st2_b[obase], bo1 = st2_b[obase+1];
        const float bo2 = st2_b[obase+2], bo3 = st2_b[obase+3];
        float s0=0.f, s1=0.f, s2=0.f, s3=0.f;
        #pragma unroll
        for (int nt=0; nt<19; nt++){
            const int p = nt*16 + m;
            if (p < 289){
                const int py = (p*241)>>12;
                const int px = p - py*17;
                const float ty = -1.f + 0.125f*py;
                const float tx = -1.f + 0.125f*px;
                const float g = expf(-3.125f*(ty*ty + tx*tx));
                s0 += g*gelu_f(acc[nt].x+bo0);
                s1 += g*gelu_f(acc[nt].y+bo1);
                s2 += g*gelu_f(acc[nt].z+bo2);
                s3 += g*gelu_f(acc[nt].w+bo3);
            }
        }
        #pragma unroll
        for (int off=1; off<16; off<<=1){
            s0 += __shfl_xor(s0, off);
            s1 += __shfl_xor(s1, off);
            s2 += __shfl_xor(s2, off);
            s3 += __shfl_xor(s3, off);
        }
        if (m == 0){
            redS[obase]   = s0;
            redS[obase+1] = s1;
            redS[obase+2] = s2;
            redS[obase+3] = s3;
        }
    }
    __syncthreads();
    if (t < 64){
        float Sv = 0.f;
        #pragma unroll
        for (int j=0;j<17;j++){
            const float tj = -1.f + 0.125f*j;
            Sv += expf(-3.125f*tj*tj);
        }
        vec_out[n*192+128+t] = redS[t] / (Sv*Sv);
    }
}

// ---------------- Head MLP + sky transform (f32 outputs) ----------------
__global__ __launch_bounds__(128) void head_kernel(
    const float* __restrict__ vec, const float* __restrict__ p2s,
    const float* __restrict__ h1_w, const float* __restrict__ h1_b,
    const float* __restrict__ h2_w, const float* __restrict__ h2_b,
    const float* __restrict__ h3_w, const float* __restrict__ h3_b,
    float* __restrict__ out, int N)
{
    __shared__ float v[192];
    __shared__ float x1[128];
    __shared__ float x2[128];
    const int n = blockIdx.x, t = threadIdx.x;
    v[t] = vec[n*192+t];
    if (t < 64) v[128+t] = vec[n*192+128+t];
    __syncthreads();
    {
        const float* w = h1_w + t*192;
        float a = h1_b[t];
        for (int k=0;k<192;k++) a += v[k]*w[k];
        x1[t] = gelu_f(a);
    }
    __syncthreads();
    {
        const float* w = h2_w + t*128;
        float a = h2_b[t];
        for (int k=0;k<128;k++) a += x1[k]*w[k];
        x2[t] = gelu_f(a);
    }
    __syncthreads();
    if (t == 0){
        float o3[3];
        #pragma unroll
        for (int j=0;j<3;j++){
            const float* w = h3_w + j*128;
            float a = h3_b[j];
            for (int k=0;k<128;k++) a += x2[k]*w[k];
            o3[j]=a;
        }
        const float dx=o3[0], dy=o3[1];
        float ls = o3[2];
        ls = ls < -6.f ? -6.f : (ls > 3.f ? 3.f : ls);
        const float s0 = p2s[n*4+0]*dx + p2s[n*4+1]*dy;
        const float s1 = p2s[n*4+2]*dx + p2s[n*4+3]*dy;
        const float conf = 1.0f/fmaxf(expf(ls), 1e-4f);
        out[2*n]   = s0;
        out[2*n+1] = s1;
        out[2*N+n] = dx;
        out[3*N+n] = dy;
        out[4*N+n] = ls;
        out[5*N+n] = conf;
    }
}

extern "C" void kernel_launch(void* const* d_in, const int* in_sizes, int n_in,
                              void* d_out, int out_size, void* d_ws, size_t ws_size,
                              hipStream_t stream)
{
    (void)n_in; (void)out_size;
    const float* bottleneck = (const float*)d_in[0];
    const float* vis        = (const float*)d_in[1];
    const float* pos        = (const float*)d_in[2];
    const float* p2s        = (const float*)d_in[3];
    const float* dw_w  = (const float*)d_in[8];
    const float* dw_b  = (const float*)d_in[9];
    const float* ln_g  = (const float*)d_in[10];
    const float* ln_b  = (const float*)d_in[11];
    const float* pw1_w = (const float*)d_in[12];
    const float* pw1_b = (const float*)d_in[13];
    const float* pw2_w = (const float*)d_in[14];
    const float* pw2_b = (const float*)d_in[15];
    const float* gam   = (const float*)d_in[16];
    const float* b1w   = (const float*)d_in[17];
    const float* b1b   = (const float*)d_in[18];
    const float* s1w   = (const float*)d_in[19];
    const float* s1b   = (const float*)d_in[20];
    const float* s2w   = (const float*)d_in[21];
    const float* s2b   = (const float*)d_in[22];
    const float* h1w   = (const float*)d_in[23];
    const float* h1b   = (const float*)d_in[24];
    const float* h2w   = (const float*)d_in[25];
    const float* h2b   = (const float*)d_in[26];
    const float* h3w   = (const float*)d_in[27];
    const float* h3b   = (const float*)d_in[28];

    const int N = in_sizes[2]/2;            // 4096
    float* vec = (float*)d_ws;              // [N][192] f32
    const size_t vec_bytes = (size_t)N*192*sizeof(float);
    unsigned short* Apack = (unsigned short*)((char*)d_ws + vec_bytes);  // stem: 147456 B
    unsigned short* P1 = Apack + 73728;          // pw1 pack: 262144 ushorts
    unsigned short* P2 = P1 + 262144;            // pw2 pack: 262144 ushorts
    unsigned short* Pb = P2 + 262144;            // bn1x1 pack: 32768 ushorts
    const size_t need = vec_bytes + 147456u + (262144u+262144u+32768u)*2u;

    prepack_kernel<<<36, 256, 0, stream>>>(s1w, s2w, Apack);

    if (ws_size >= need){
        prepack_bn_kernel<<<272, 256, 0, stream>>>(pw1_w, pw2_w, b1w, P1, P2, Pb);
        bn_branch_mfma<<<N, 512, 0, stream>>>(bottleneck, pos, dw_w, dw_b, ln_g, ln_b,
                                              pw1_b, pw2_b, gam, b1b,
                                              (const short8*)P1, (const short8*)P2, (const short8*)Pb,
                                              vec);
    } else {
        bn_branch_valu<<<N, 256, 0, stream>>>(bottleneck, pos, dw_w, dw_b, ln_g, ln_b,
                                              pw1_w, pw1_b, pw2_w, pw2_b, gam, b1w, b1b, vec);
    }
    stem_branch_kernel<<<N, 256, 0, stream>>>(vis, pos, (const short8*)Apack, s1b, s2b, vec);
    head_kernel<<<N, 128, 0, stream>>>(vec, p2s, h1w, h1b, h2w, h2b, h3w, h3b,
                                       (float*)d_out, N);
}

// Round 7
// 907.407 us; speedup vs baseline: 22.3144x; 1.2659x over previous
//
#include <hip/hip_runtime.h>
#include <hip/hip_bf16.h>

#define XSTR 28   // legacy BN VALU kernel stride

typedef short short8 __attribute__((ext_vector_type(8)));
typedef float f32x4  __attribute__((ext_vector_type(4)));

__device__ __forceinline__ float gelu_f(float x){
    return 0.5f*x*(1.0f + erff(x*0.70710678118654752f));
}
// fast gelu: x*sigmoid(1.702x), |err| <= 0.0203
__device__ __forceinline__ float gelu_q(float x){
    return x / (1.0f + __expf(-1.702f*x));
}
__device__ __forceinline__ unsigned short f2bf(float f){
    unsigned int u = __float_as_uint(f);
    u += 0x7fffu + ((u>>16)&1u);
    return (unsigned short)(u>>16);
}
__device__ __forceinline__ unsigned int pack2(float a, float b){
    return (unsigned int)f2bf(a) | ((unsigned int)f2bf(b)<<16);
}
__device__ __forceinline__ float bf_lo(unsigned int u){ return __uint_as_float(u<<16); }
__device__ __forceinline__ float bf_hi(unsigned int u){ return __uint_as_float(u & 0xffff0000u); }
__device__ __forceinline__ float bfu(unsigned short v){ return __uint_as_float(((unsigned int)v)<<16); }

__device__ __forceinline__ void fma_row25(const float* __restrict__ row, float w, float* __restrict__ acc){
    const float4* r4 = (const float4*)row;
    float4 a0=r4[0], a1=r4[1], a2=r4[2], a3=r4[3], a4=r4[4], a5=r4[5];
    float a6 = row[24];
    acc[0]+=a0.x*w;  acc[1]+=a0.y*w;  acc[2]+=a0.z*w;  acc[3]+=a0.w*w;
    acc[4]+=a1.x*w;  acc[5]+=a1.y*w;  acc[6]+=a1.z*w;  acc[7]+=a1.w*w;
    acc[8]+=a2.x*w;  acc[9]+=a2.y*w;  acc[10]+=a2.z*w; acc[11]+=a2.w*w;
    acc[12]+=a3.x*w; acc[13]+=a3.y*w; acc[14]+=a3.z*w; acc[15]+=a3.w*w;
    acc[16]+=a4.x*w; acc[17]+=a4.y*w; acc[18]+=a4.z*w; acc[19]+=a4.w*w;
    acc[20]+=a5.x*w; acc[21]+=a5.y*w; acc[22]+=a5.z*w; acc[23]+=a5.w*w;
    acc[24]+=a6*w;
}

// ================= BN branch, MFMA, 2 samples per block =================
// Xb [64 rows][512B] bf16 (row = s*32+p), Hc [64][256B]; XOR swizzle ((row&7)<<4).
__global__ __launch_bounds__(512,4) void bn_branch_mfma(
    const float* __restrict__ bottleneck, const float* __restrict__ pos,
    const float* __restrict__ dw_w, const float* __restrict__ dw_b,
    const float* __restrict__ ln_g, const float* __restrict__ ln_b,
    const float* __restrict__ pw1_b, const float* __restrict__ pw2_b,
    const float* __restrict__ cn_gamma, const float* __restrict__ bn1x1_b,
    const short8* __restrict__ P1v, const short8* __restrict__ P2v,
    const short8* __restrict__ Pbv,
    float* __restrict__ vec_out)
{
    __shared__ __align__(16) unsigned char Xb[64*512];   // 32KB
    __shared__ __align__(16) unsigned char Hc[64*256];   // 16KB
    __shared__ float redA[400], redB[400], muS[56], rsS[56];

    const int n0 = blockIdx.x*2, t = threadIdx.x;
    const int lane = t & 63, w = t >> 6;
    const int mcol = lane & 15, h4 = lane >> 4;
    const int sP = t >> 8, cP = t & 255;   // preamble: thread = (sample, channel)

    unsigned int wvp[13];   // residual, packed bf16 pairs (lives across GEMM)
    float xdw[25];          // dw output (dies after normalize)
    {
        const int n = n0 + sP;
        const float px = pos[2*n]*0.125f, py = pos[2*n+1]*0.125f;
        const float fpx = floorf(px), fpy = floorf(py);
        const int ix0 = (int)fpx - 2, iy0 = (int)fpy - 2;
        const float fx = px - fpx, fy = py - fpy;
        const float w00=(1.f-fy)*(1.f-fx), w01=(1.f-fy)*fx, w10=fy*(1.f-fx), w11=fy*fx;
        float wv[25];
        {
            const float* fm = bottleneck + cP*16384;
            float P[6][6];
            #pragma unroll
            for (int r=0;r<6;r++){
                const int y = iy0+r;
                const bool yok = (y>=0)&&(y<128);
                const int yc = y<0?0:(y>127?127:y);
                #pragma unroll
                for (int s=0;s<6;s++){
                    const int x = ix0+s;
                    const bool ok = yok && (x>=0) && (x<128);
                    const int xc = x<0?0:(x>127?127:x);
                    P[r][s] = ok ? fm[yc*128+xc] : 0.f;
                }
            }
            #pragma unroll
            for (int a=0;a<5;a++)
            #pragma unroll
            for (int b=0;b<5;b++)
                wv[a*5+b] = w00*P[a][b]+w01*P[a][b+1]+w10*P[a+1][b]+w11*P[a+1][b+1];
        }
        #pragma unroll
        for (int i=0;i<12;i++) wvp[i] = pack2(wv[2*i], wv[2*i+1]);
        wvp[12] = pack2(wv[24], 0.f);
        // depthwise 7x7 (zero-padded 5x5)
        {
            float wcr[49];
            const float* wc = dw_w + cP*49;
            #pragma unroll
            for (int k=0;k<49;k++) wcr[k]=wc[k];
            const float bb = dw_b[cP];
            #pragma unroll
            for (int i=0;i<5;i++){
                #pragma unroll
                for (int j=0;j<5;j++){
                    float a = bb;
                    #pragma unroll
                    for (int u=0;u<7;u++){
                        const int y = i+u-3;
                        if (y<0||y>4) continue;
                        #pragma unroll
                        for (int v=0;v<7;v++){
                            const int x = j+v-3;
                            if (x<0||x>4) continue;
                            a += wv[y*5+x]*wcr[u*7+v];
                        }
                    }
                    xdw[i*5+j] = a;
                }
            }
        }
        // write dw output (bf16) for LN stats
        #pragma unroll
        for (int p=0;p<25;p++){
            const int row = sP*32 + p;
            *(unsigned short*)(Xb + row*512 + ((2*cP) ^ ((row&7)<<4))) = f2bf(xdw[p]);
        }
    }
    __syncthreads();
    // ---- LN stats: 50 positions x 8 partials ----
    if (t < 400){
        const int sp = t>>3, part = t&7;
        const int row = (sp/25)*32 + (sp - (sp/25)*25);
        float a=0.f, b=0.f;
        for (int c=part; c<256; c+=8){
            const float v = bfu(*(const unsigned short*)(Xb + row*512 + ((2*c) ^ ((row&7)<<4))));
            a += v; b += v*v;
        }
        redA[t]=a; redB[t]=b;
    }
    __syncthreads();
    if (t < 50){
        float a=0.f, b=0.f;
        #pragma unroll
        for (int s=0;s<8;s++){ a+=redA[t*8+s]; b+=redB[t*8+s]; }
        const float m = a*(1.f/256.f);
        const float var = b*(1.f/256.f) - m*m;
        muS[t]=m; rsS[t]=rsqrtf(var+1e-6f);
    }
    __syncthreads();
    // ---- normalize from registers, overwrite Xb ----
    {
        const float g = ln_g[cP], bb = ln_b[cP];
        #pragma unroll
        for (int p=0;p<25;p++){
            const int row = sP*32 + p;
            const float v = (xdw[p]-muS[sP*25+p])*rsS[sP*25+p]*g + bb;
            *(unsigned short*)(Xb + row*512 + ((2*cP) ^ ((row&7)<<4))) = f2bf(v);
        }
    }
    __syncthreads();

    // ---- chunked pw1 -> pw2, 4 N-tiles (2 samples) ----
    f32x4 acc2[2][4];
    #pragma unroll
    for (int ml=0;ml<2;ml++)
        #pragma unroll
        for (int nt=0;nt<4;nt++) acc2[ml][nt]=0.f;

    for (int ch=0; ch<8; ++ch){
        const int mt = ch*8 + w;
        f32x4 a1[4];
        #pragma unroll
        for (int nt=0;nt<4;nt++) a1[nt]=0.f;
        #pragma unroll
        for (int kk=0; kk<8; ++kk){
            const short8 av = P1v[((mt<<3)+kk)*64 + lane];
            #pragma unroll
            for (int nt=0; nt<4; ++nt){
                const int row = nt*16 + mcol;
                const int ad = row*512 + ((kk*64 + h4*16) ^ ((row&7)<<4));
                const short8 bv = *(const short8*)(Xb + ad);
                a1[nt] = __builtin_amdgcn_mfma_f32_16x16x32_bf16(av, bv, a1[nt], 0,0,0);
            }
        }
        {
            const float4 b1v = *(const float4*)(pw1_b + mt*16 + h4*4);
            #pragma unroll
            for (int nt=0; nt<4; ++nt){
                const int row = nt*16 + mcol;
                const float g0 = gelu_q(a1[nt].x + b1v.x);
                const float g1 = gelu_q(a1[nt].y + b1v.y);
                const float g2 = gelu_q(a1[nt].z + b1v.z);
                const float g3 = gelu_q(a1[nt].w + b1v.w);
                const int ad = row*256 + ((w*32 + h4*8) ^ ((row&7)<<4));
                *(uint2*)(Hc + ad) = make_uint2(pack2(g0,g1), pack2(g2,g3));
            }
        }
        __syncthreads();
        #pragma unroll
        for (int ml=0; ml<2; ++ml){
            const int mtc = w*2 + ml;
            #pragma unroll
            for (int kk2=0; kk2<4; ++kk2){
                const short8 av = P2v[(mtc*32 + (ch*4 + kk2))*64 + lane];
                #pragma unroll
                for (int nt=0; nt<4; ++nt){
                    const int row = nt*16 + mcol;
                    const int ad = row*256 + ((kk2*64 + h4*16) ^ ((row&7)<<4));
                    const short8 bv = *(const short8*)(Hc + ad);
                    acc2[ml][nt] = __builtin_amdgcn_mfma_f32_16x16x32_bf16(av, bv, acc2[ml][nt], 0,0,0);
                }
            }
        }
        __syncthreads();
    }

    // ---- pw2 epilogue: gamma*(acc+b2) -> Xb (residual added next phase) ----
    #pragma unroll
    for (int ml=0; ml<2; ++ml){
        const int c0 = (w*2+ml)*16 + h4*4;
        const float4 gm = *(const float4*)(cn_gamma + c0);
        const float4 b2 = *(const float4*)(pw2_b + c0);
        #pragma unroll
        for (int nt=0; nt<4; ++nt){
            const int row = nt*16 + mcol;
            const int ad = row*512 + ((2*c0) ^ ((row&7)<<4));
            const float f0 = gm.x*(acc2[ml][nt].x + b2.x);
            const float f1 = gm.y*(acc2[ml][nt].y + b2.y);
            const float f2 = gm.z*(acc2[ml][nt].z + b2.z);
            const float f3 = gm.w*(acc2[ml][nt].w + b2.w);
            *(uint2*)(Xb + ad) = make_uint2(pack2(f0,f1), pack2(f2,f3));
        }
    }
    __syncthreads();
    // ---- residual add (preamble threads own their (s,c)) ----
    #pragma unroll
    for (int p=0;p<25;p++){
        const int row = sP*32 + p;
        unsigned short* ptr = (unsigned short*)(Xb + row*512 + ((2*cP) ^ ((row&7)<<4)));
        const float r = (p&1) ? bf_hi(wvp[p>>1]) : bf_lo(wvp[p>>1]);
        *ptr = f2bf(bfu(*ptr) + r);
    }
    __syncthreads();

    // ---- bn1x1 + gelu + gauss(5), both samples ----
    {
        f32x4 a3[4];
        #pragma unroll
        for (int nt=0;nt<4;nt++) a3[nt]=0.f;
        #pragma unroll
        for (int kk=0; kk<8; ++kk){
            const short8 av = Pbv[((w<<3)+kk)*64 + lane];
            #pragma unroll
            for (int nt=0; nt<4; ++nt){
                const int row = nt*16 + mcol;
                const int ad = row*512 + ((kk*64 + h4*16) ^ ((row&7)<<4));
                const short8 bv = *(const short8*)(Xb + ad);
                a3[nt] = __builtin_amdgcn_mfma_f32_16x16x32_bf16(av, bv, a3[nt], 0,0,0);
            }
        }
        const float4 bb = *(const float4*)(bn1x1_b + w*16 + h4*4);
        float e5[5];
        #pragma unroll
        for (int a=0;a<5;a++){
            const float ta = -1.f + 0.5f*a;
            e5[a] = expf(-3.125f*ta*ta);
        }
        const float Sv = e5[0]+e5[1]+e5[2]+e5[3]+e5[4];
        const float invS = 1.0f/(Sv*Sv);
        float sA[2][4];
        #pragma unroll
        for (int s=0;s<2;s++)
            #pragma unroll
            for (int j=0;j<4;j++) sA[s][j]=0.f;
        #pragma unroll
        for (int nt=0; nt<4; ++nt){
            const int row = nt*16 + mcol;
            const int s = row>>5, p = row&31;
            if (p < 25){
                const int pa = p/5, pb = p - pa*5;
                const float g = e5[pa]*e5[pb];
                sA[s][0] += g*gelu_q(a3[nt].x + bb.x);
                sA[s][1] += g*gelu_q(a3[nt].y + bb.y);
                sA[s][2] += g*gelu_q(a3[nt].z + bb.z);
                sA[s][3] += g*gelu_q(a3[nt].w + bb.w);
            }
        }
        #pragma unroll
        for (int off=1; off<16; off<<=1){
            #pragma unroll
            for (int s=0;s<2;s++)
                #pragma unroll
                for (int j=0;j<4;j++) sA[s][j] += __shfl_xor(sA[s][j], off);
        }
        if (mcol == 0){
            const int o = w*16 + h4*4;
            #pragma unroll
            for (int s=0;s<2;s++){
                float* vo = vec_out + (n0+s)*192 + o;
                vo[0]=sA[s][0]*invS; vo[1]=sA[s][1]*invS;
                vo[2]=sA[s][2]*invS; vo[3]=sA[s][3]*invS;
            }
        }
    }
}

// ---- bn weight prepack (fixed bounds, proven) ----
__global__ __launch_bounds__(256) void prepack_bn_kernel(
    const float* __restrict__ W1, const float* __restrict__ W2, const float* __restrict__ Wb,
    unsigned short* __restrict__ P1, unsigned short* __restrict__ P2, unsigned short* __restrict__ Pb)
{
    const int tid = blockIdx.x*256 + threadIdx.x;
    const float* src; unsigned short* dst; int row, col, stride, idx;
    if (tid < 32768){
        idx = tid;
        const int frag = idx>>6, l = idx&63;
        row = (frag>>3)*16 + (l&15); col = (frag&7)*32 + (l>>4)*8; stride = 256;
        src = W1; dst = P1;
    } else if (tid < 65536){
        idx = tid - 32768;
        const int frag = idx>>6, l = idx&63;
        row = (frag>>5)*16 + (l&15); col = (frag&31)*32 + (l>>4)*8; stride = 1024;
        src = W2; dst = P2;
    } else if (tid < 69632){
        idx = tid - 65536;
        const int frag = idx>>6, l = idx&63;
        row = (frag>>3)*16 + (l&15); col = (frag&7)*32 + (l>>4)*8; stride = 256;
        src = Wb; dst = Pb;
    } else return;
    const float* s = src + row*stride + col;
    unsigned int v[4];
    #pragma unroll
    for (int j=0;j<4;j++) v[j] = pack2(s[2*j], s[2*j+1]);
    *(uint4*)(dst + (size_t)idx*8) = make_uint4(v[0],v[1],v[2],v[3]);
}

// ================= BN branch, VALU fallback (proven) =================
__global__ __launch_bounds__(256,2) void bn_branch_valu(
    const float* __restrict__ bottleneck, const float* __restrict__ pos,
    const float* __restrict__ dw_w, const float* __restrict__ dw_b,
    const float* __restrict__ ln_g, const float* __restrict__ ln_b,
    const float* __restrict__ pw1_w, const float* __restrict__ pw1_b,
    const float* __restrict__ pw2_w, const float* __restrict__ pw2_b,
    const float* __restrict__ cn_gamma,
    const float* __restrict__ bn1x1_w, const float* __restrict__ bn1x1_b,
    float* __restrict__ vec_out)
{
    __shared__ float xln[256*XSTR];
    __shared__ float hbuf[256*XSTR];
    __shared__ float redA[200], redB[200];
    __shared__ float mu[25], rs[25];

    const int n = blockIdx.x;
    const int t = threadIdx.x;
    const int c = t;

    const float px = pos[2*n]*0.125f, py = pos[2*n+1]*0.125f;
    const float fpx = floorf(px), fpy = floorf(py);
    const int ix0 = (int)fpx - 2, iy0 = (int)fpy - 2;
    const float fx = px - fpx, fy = py - fpy;
    const float w00=(1.f-fy)*(1.f-fx), w01=(1.f-fy)*fx, w10=fy*(1.f-fx), w11=fy*fx;

    float wv[25];
    {
        const float* fm = bottleneck + c*16384;
        float P[6][6];
        #pragma unroll
        for (int r=0;r<6;r++){
            const int y = iy0+r;
            const bool yok = (y>=0)&&(y<128);
            const int yc = y<0?0:(y>127?127:y);
            #pragma unroll
            for (int s=0;s<6;s++){
                const int x = ix0+s;
                const bool ok = yok && (x>=0) && (x<128);
                const int xc = x<0?0:(x>127?127:x);
                P[r][s] = ok ? fm[yc*128+xc] : 0.f;
            }
        }
        #pragma unroll
        for (int a=0;a<5;a++)
        #pragma unroll
        for (int b=0;b<5;b++)
            wv[a*5+b] = w00*P[a][b]+w01*P[a][b+1]+w10*P[a+1][b]+w11*P[a+1][b+1];
    }
    {
        float wcr[49];
        const float* wc = dw_w + c*49;
        #pragma unroll
        for (int k=0;k<49;k++) wcr[k]=wc[k];
        const float bb = dw_b[c];
        #pragma unroll
        for (int i=0;i<5;i++){
            #pragma unroll
            for (int j=0;j<5;j++){
                float a = bb;
                #pragma unroll
                for (int u=0;u<7;u++){
                    const int y = i+u-3;
                    if (y<0||y>4) continue;
                    #pragma unroll
                    for (int v=0;v<7;v++){
                        const int x = j+v-3;
                        if (x<0||x>4) continue;
                        a += wv[y*5+x]*wcr[u*7+v];
                    }
                }
                xln[c*XSTR + i*5+j] = a;
            }
        }
    }
    __syncthreads();
    if (t < 200){
        const int p = t>>3, s = t&7;
        float a=0.f, b=0.f;
        for (int cc=s; cc<256; cc+=8){
            const float v = xln[cc*XSTR+p];
            a += v; b += v*v;
        }
        redA[t]=a; redB[t]=b;
    }
    __syncthreads();
    if (t < 25){
        float a=0.f, b=0.f;
        #pragma unroll
        for (int s=0;s<8;s++){ a+=redA[t*8+s]; b+=redB[t*8+s]; }
        const float m = a*(1.f/256.f);
        const float var = b*(1.f/256.f) - m*m;
        mu[t]=m; rs[t]=rsqrtf(var+1e-6f);
    }
    __syncthreads();
    {
        const float g = ln_g[c], bb = ln_b[c];
        #pragma unroll
        for (int p=0;p<25;p++)
            xln[c*XSTR+p] = (xln[c*XSTR+p]-mu[p])*rs[p]*g + bb;
    }
    __syncthreads();
    float acc2[25];
    #pragma unroll
    for (int p=0;p<25;p++) acc2[p]=0.f;
    for (int r=0;r<4;r++){
        const int o = r*256 + t;
        float h[25];
        {
            const float b1 = pw1_b[o];
            #pragma unroll
            for (int p=0;p<25;p++) h[p]=b1;
            const float* wr = pw1_w + o*256;
            for (int cc=0;cc<256;cc++)
                fma_row25(xln + cc*XSTR, wr[cc], h);
            #pragma unroll
            for (int p=0;p<25;p++) h[p]=gelu_f(h[p]);
        }
        __syncthreads();
        #pragma unroll
        for (int p=0;p<25;p++) hbuf[t*XSTR+p]=h[p];
        __syncthreads();
        {
            const float* w2 = pw2_w + t*1024 + r*256;
            for (int k=0;k<256;k++)
                fma_row25(hbuf + k*XSTR, w2[k], acc2);
        }
    }
    {
        const float gam = cn_gamma[c], b2 = pw2_b[c];
        #pragma unroll
        for (int p=0;p<25;p++)
            xln[c*XSTR+p] = wv[p] + gam*(acc2[p]+b2);
    }
    __syncthreads();
    if (t < 128){
        float acc[25];
        #pragma unroll
        for (int p=0;p<25;p++) acc[p]=0.f;
        const float* wr = bn1x1_w + t*256;
        for (int cc=0;cc<256;cc++)
            fma_row25(xln + cc*XSTR, wr[cc], acc);
        const float b = bn1x1_b[t];
        float e5[5];
        #pragma unroll
        for (int a=0;a<5;a++){
            const float ta = -1.f + 0.5f*a;
            e5[a] = expf(-3.125f*ta*ta);
        }
        const float Sv = e5[0]+e5[1]+e5[2]+e5[3]+e5[4];
        float res = 0.f;
        #pragma unroll
        for (int a=0;a<5;a++){
            float rowa = 0.f;
            #pragma unroll
            for (int bb=0;bb<5;bb++)
                rowa += e5[bb]*gelu_f(acc[a*5+bb]+b);
            res += e5[a]*rowa;
        }
        vec_out[n*192+t] = res/(Sv*Sv);
    }
}

// ---------------- Stem weight prepack (unchanged, proven) ----------------
__global__ __launch_bounds__(256) void prepack_kernel(
    const float* __restrict__ W1, const float* __restrict__ W2,
    unsigned short* __restrict__ Ap)
{
    const int tid = blockIdx.x*256 + threadIdx.x;
    if (tid >= 9216) return;
    int r = tid;
    const int conv = r / 4608; r -= conv*4608;
    const int k = r / 512;     r -= k*512;
    const int s = r / 256;     r -= s*256;
    const int w = r / 64;
    const int l = r - w*64;
    const float* W = conv ? W2 : W1;
    const int o  = w*16 + (l & 15);
    const int c0 = s*32 + (l >> 4)*8;
    unsigned int v[4];
    #pragma unroll
    for (int jj=0; jj<4; jj++){
        const float f0 = W[o*576 + (c0+2*jj  )*9 + k];
        const float f1 = W[o*576 + (c0+2*jj+1)*9 + k];
        v[jj] = pack2(f0, f1);
    }
    uint4* dst = (uint4*)(Ap + (size_t)tid*8);
    *dst = make_uint4(v[0], v[1], v[2], v[3]);
}

// ---------------- Stem branch: MFMA version (unchanged, proven) ----------------
#define STEM_CONV(SRC, AP, ACC)                                                     \
    for (int k=0;k<9;k++){                                                          \
        const int dy = k/3 - 1, dx = (k - (k/3)*3) - 1;                             \
        for (int s=0;s<2;s++){                                                      \
            const short8 av = (AP)[k*512 + s*256 + w*64 + lane];                    \
            const int cb = s*64 + h*16;                                             \
            _Pragma("unroll")                                                       \
            for (int nt=0; nt<19; nt++){                                            \
                const int p  = nt*16 + m;                                           \
                const int py = (p*241)>>12;                                         \
                const int px = p - py*17;                                           \
                const int y = py + dy, x = px + dx;                                 \
                const bool ok = ((unsigned)y < 17u) && ((unsigned)x < 17u);         \
                const int pp = ok ? (y*17 + x) : 305;                               \
                const int ad = pp*128 + (cb ^ ((pp&7)<<4));                         \
                const short8 bv = *(const short8*)((SRC) + ad);                     \
                ACC[nt] = __builtin_amdgcn_mfma_f32_16x16x32_bf16(av, bv, ACC[nt], 0, 0, 0); \
            }                                                                       \
        }                                                                           \
    }

__global__ __launch_bounds__(256,2) void stem_branch_kernel(
    const float* __restrict__ vis,
    const float* __restrict__ pos,
    const short8* __restrict__ Ap1,
    const float* __restrict__ st1_b,
    const float* __restrict__ st2_b,
    float* __restrict__ vec_out)
{
    __shared__ __align__(16) unsigned char sXt[306*128];
    __shared__ __align__(16) unsigned char sC1[306*128];
    __shared__ float redS[64];

    const int n = blockIdx.x;
    const int t = threadIdx.x;
    const int lane = t & 63;
    const int m = t & 15;
    const int h = (t >> 4) & 3;
    const int w = t >> 6;

    const float fpx0 = pos[2*n], fpy0 = pos[2*n+1];
    const float fpx = floorf(fpx0), fpy = floorf(fpy0);
    const int ix0 = (int)fpx - 8, iy0 = (int)fpy - 8;
    const float fx = fpx0-fpx, fy = fpy0-fpy;
    const float w00=(1.f-fy)*(1.f-fx), w01=(1.f-fy)*fx, w10=fy*(1.f-fx), w11=fy*fx;

    if (t < 32)      *(unsigned int*)(sXt + 305*128 + t*4) = 0u;
    else if (t < 64) *(unsigned int*)(sC1 + 305*128 + (t-32)*4) = 0u;

    for (int task = t; task < 64*17; task += 256){
        const int c  = task & 63;
        const int py = task >> 6;
        const float* r0 = vis + c*1048576 + (iy0+py)*1024 + ix0;
        float a[18], b[18];
        #pragma unroll
        for (int kk=0; kk<18; kk++){ a[kk]=r0[kk]; b[kk]=r0[1024+kk]; }
        #pragma unroll
        for (int px=0; px<17; px++){
            const float v = w00*a[px] + w01*a[px+1] + w10*b[px] + w11*b[px+1];
            const int p = py*17 + px;
            *(unsigned short*)(sXt + p*128 + ((2*c) ^ ((p&7)<<4))) = f2bf(v);
        }
    }
    __syncthreads();

    f32x4 acc[19];
    #pragma unroll
    for (int nt=0; nt<19; nt++) acc[nt] = 0.f;
    STEM_CONV(sXt, Ap1, acc)

    {
        const int obase = w*16 + h*4;
        const float bo0 = st1_b[obase], bo1 = st1_b[obase+1];
        const float bo2 = st1_b[obase+2], bo3 = st1_b[obase+3];
        #pragma unroll
        for (int nt=0; nt<19; nt++){
            const int p = nt*16 + m;
            if (p < 304){
                const unsigned r01 = pack2(gelu_f(acc[nt].x+bo0), gelu_f(acc[nt].y+bo1));
                const unsigned r23 = pack2(gelu_f(acc[nt].z+bo2), gelu_f(acc[nt].w+bo3));
                const int ad = p*128 + ((2*obase) ^ ((p&7)<<4));
                *(uint2*)(sC1 + ad) = make_uint2(r01, r23);
            }
        }
    }
    __syncthreads();

    const short8* Ap2 = Ap1 + 4608;
    #pragma unroll
    for (int nt=0; nt<19; nt++) acc[nt] = 0.f;
    STEM_CONV(sC1, Ap2, acc)

    {
        const int obase = w*16 + h*4;
        const float bo0 = st2_b[obase], bo1 = st2_b[obase+1];
        const float bo2 = st2_b[obase+2], bo3 = st2_b[obase+3];
        float s0=0.f, s1=0.f, s2=0.f, s3=0.f;
        #pragma unroll
        for (int nt=0; nt<19; nt++){
            const int p = nt*16 + m;
            if (p < 289){
                const int py = (p*241)>>12;
                const int px = p - py*17;
                const float ty = -1.f + 0.125f*py;
                const float tx = -1.f + 0.125f*px;
                const float g = expf(-3.125f*(ty*ty + tx*tx));
                s0 += g*gelu_f(acc[nt].x+bo0);
                s1 += g*gelu_f(acc[nt].y+bo1);
                s2 += g*gelu_f(acc[nt].z+bo2);
                s3 += g*gelu_f(acc[nt].w+bo3);
            }
        }
        #pragma unroll
        for (int off=1; off<16; off<<=1){
            s0 += __shfl_xor(s0, off);
            s1 += __shfl_xor(s1, off);
            s2 += __shfl_xor(s2, off);
            s3 += __shfl_xor(s3, off);
        }
        if (m == 0){
            redS[obase]   = s0;
            redS[obase+1] = s1;
            redS[obase+2] = s2;
            redS[obase+3] = s3;
        }
    }
    __syncthreads();
    if (t < 64){
        float Sv = 0.f;
        #pragma unroll
        for (int j=0;j<17;j++){
            const float tj = -1.f + 0.125f*j;
            Sv += expf(-3.125f*tj*tj);
        }
        vec_out[n*192+128+t] = redS[t] / (Sv*Sv);
    }
}

// ---------------- Head: 16 samples/block, register-blocked GEMV ----------------
__global__ __launch_bounds__(128) void head16_kernel(
    const float* __restrict__ vec, const float* __restrict__ p2s,
    const float* __restrict__ h1_w, const float* __restrict__ h1_b,
    const float* __restrict__ h2_w, const float* __restrict__ h2_b,
    const float* __restrict__ h3_w, const float* __restrict__ h3_b,
    float* __restrict__ out, int N)
{
    __shared__ float v[16][192];
    __shared__ float x1s[16][132];
    __shared__ float x2s[16][132];
    __shared__ float o3s[16][4];
    const int n0 = blockIdx.x*16, t = threadIdx.x;

    for (int idx=t; idx<16*192; idx+=128){
        const int s = idx/192, k = idx - s*192;
        v[s][k] = vec[n0*192 + idx];
    }
    __syncthreads();
    // h1: 192 -> 128
    {
        const int o = t;
        float acc[16];
        const float b = h1_b[o];
        #pragma unroll
        for (int s=0;s<16;s++) acc[s]=b;
        const float4* wr = (const float4*)(h1_w + o*192);
        for (int k4=0;k4<48;k4++){
            const float4 wv4 = wr[k4];
            #pragma unroll
            for (int s=0;s<16;s++){
                const float4 vv = *(const float4*)&v[s][k4*4];
                acc[s] += wv4.x*vv.x + wv4.y*vv.y + wv4.z*vv.z + wv4.w*vv.w;
            }
        }
        #pragma unroll
        for (int s=0;s<16;s++) x1s[s][o] = gelu_f(acc[s]);
    }
    __syncthreads();
    // h2: 128 -> 128
    {
        const int o = t;
        float acc[16];
        const float b = h2_b[o];
        #pragma unroll
        for (int s=0;s<16;s++) acc[s]=b;
        const float4* wr = (const float4*)(h2_w + o*128);
        for (int k4=0;k4<32;k4++){
            const float4 wv4 = wr[k4];
            #pragma unroll
            for (int s=0;s<16;s++){
                const float4 vv = *(const float4*)&x1s[s][k4*4];
                acc[s] += wv4.x*vv.x + wv4.y*vv.y + wv4.z*vv.z + wv4.w*vv.w;
            }
        }
        #pragma unroll
        for (int s=0;s<16;s++) x2s[s][o] = gelu_f(acc[s]);
    }
    __syncthreads();
    // h3: 128 -> 3
    if (t < 48){
        const int j = t>>4, s = t&15;
        float a = h3_b[j];
        const float* wr = h3_w + j*128;
        for (int k=0;k<128;k++) a += x2s[s][k]*wr[k];
        o3s[s][j] = a;
    }
    __syncthreads();
    if (t < 16){
        const int s = t, n = n0 + s;
        const float dx = o3s[s][0], dy = o3s[s][1];
        float ls = o3s[s][2];
        ls = ls < -6.f ? -6.f : (ls > 3.f ? 3.f : ls);
        const float s0 = p2s[n*4+0]*dx + p2s[n*4+1]*dy;
        const float s1 = p2s[n*4+2]*dx + p2s[n*4+3]*dy;
        const float conf = 1.0f/fmaxf(expf(ls), 1e-4f);
        out[2*n]   = s0;
        out[2*n+1] = s1;
        out[2*N+n] = dx;
        out[3*N+n] = dy;
        out[4*N+n] = ls;
        out[5*N+n] = conf;
    }
}

extern "C" void kernel_launch(void* const* d_in, const int* in_sizes, int n_in,
                              void* d_out, int out_size, void* d_ws, size_t ws_size,
                              hipStream_t stream)
{
    (void)n_in; (void)out_size;
    const float* bottleneck = (const float*)d_in[0];
    const float* vis        = (const float*)d_in[1];
    const float* pos        = (const float*)d_in[2];
    const float* p2s        = (const float*)d_in[3];
    const float* dw_w  = (const float*)d_in[8];
    const float* dw_b  = (const float*)d_in[9];
    const float* ln_g  = (const float*)d_in[10];
    const float* ln_b  = (const float*)d_in[11];
    const float* pw1_w = (const float*)d_in[12];
    const float* pw1_b = (const float*)d_in[13];
    const float* pw2_w = (const float*)d_in[14];
    const float* pw2_b = (const float*)d_in[15];
    const float* gam   = (const float*)d_in[16];
    const float* b1w   = (const float*)d_in[17];
    const float* b1b   = (const float*)d_in[18];
    const float* s1w   = (const float*)d_in[19];
    const float* s1b   = (const float*)d_in[20];
    const float* s2w   = (const float*)d_in[21];
    const float* s2b   = (const float*)d_in[22];
    const float* h1w   = (const float*)d_in[23];
    const float* h1b   = (const float*)d_in[24];
    const float* h2w   = (const float*)d_in[25];
    const float* h2b   = (const float*)d_in[26];
    const float* h3w   = (const float*)d_in[27];
    const float* h3b   = (const float*)d_in[28];

    const int N = in_sizes[2]/2;            // 4096
    float* vec = (float*)d_ws;              // [N][192] f32
    const size_t vec_bytes = (size_t)N*192*sizeof(float);
    unsigned short* Apack = (unsigned short*)((char*)d_ws + vec_bytes);  // stem: 147456 B
    unsigned short* P1 = Apack + 73728;
    unsigned short* P2 = P1 + 262144;
    unsigned short* Pb = P2 + 262144;
    const size_t need = vec_bytes + 147456u + (262144u+262144u+32768u)*2u;

    hipMemsetAsync(d_ws, 0, vec_bytes, stream);

    prepack_kernel<<<36, 256, 0, stream>>>(s1w, s2w, Apack);

    if (ws_size >= need){
        prepack_bn_kernel<<<272, 256, 0, stream>>>(pw1_w, pw2_w, b1w, P1, P2, Pb);
        bn_branch_mfma<<<N/2, 512, 0, stream>>>(bottleneck, pos, dw_w, dw_b, ln_g, ln_b,
                                                pw1_b, pw2_b, gam, b1b,
                                                (const short8*)P1, (const short8*)P2, (const short8*)Pb,
                                                vec);
    } else {
        bn_branch_valu<<<N, 256, 0, stream>>>(bottleneck, pos, dw_w, dw_b, ln_g, ln_b,
                                              pw1_w, pw1_b, pw2_w, pw2_b, gam, b1w, b1b, vec);
    }
    stem_branch_kernel<<<N, 256, 0, stream>>>(vis, pos, (const short8*)Apack, s1b, s2b, vec);
    head16_kernel<<<N/16, 128, 0, stream>>>(vec, p2s, h1w, h1b, h2w, h2b, h3w, h3b,
                                            (float*)d_out, N);
}

// Round 8
// 866.033 us; speedup vs baseline: 23.3805x; 1.0478x over previous
//
#include <hip/hip_runtime.h>
#include <hip/hip_bf16.h>

#define XSTR 28   // legacy BN VALU kernel stride

typedef short short8 __attribute__((ext_vector_type(8)));
typedef float f32x4  __attribute__((ext_vector_type(4)));

__device__ __forceinline__ float gelu_f(float x){
    return 0.5f*x*(1.0f + erff(x*0.70710678118654752f));
}
// fast gelu, tanh form: x*sigmoid(1.5958(x+0.044715x^3)), |err| <= ~3e-4
__device__ __forceinline__ float gelu_q(float x){
    const float z = 1.5957691216057308f*x*(1.0f + 0.044715f*x*x);
    return x / (1.0f + __expf(-z));
}
__device__ __forceinline__ unsigned short f2bf(float f){
    unsigned int u = __float_as_uint(f);
    u += 0x7fffu + ((u>>16)&1u);
    return (unsigned short)(u>>16);
}
__device__ __forceinline__ unsigned int pack2(float a, float b){
    return (unsigned int)f2bf(a) | ((unsigned int)f2bf(b)<<16);
}
__device__ __forceinline__ float bf_lo(unsigned int u){ return __uint_as_float(u<<16); }
__device__ __forceinline__ float bf_hi(unsigned int u){ return __uint_as_float(u & 0xffff0000u); }
__device__ __forceinline__ float bfu(unsigned short v){ return __uint_as_float(((unsigned int)v)<<16); }

__device__ __forceinline__ void fma_row25(const float* __restrict__ row, float w, float* __restrict__ acc){
    const float4* r4 = (const float4*)row;
    float4 a0=r4[0], a1=r4[1], a2=r4[2], a3=r4[3], a4=r4[4], a5=r4[5];
    float a6 = row[24];
    acc[0]+=a0.x*w;  acc[1]+=a0.y*w;  acc[2]+=a0.z*w;  acc[3]+=a0.w*w;
    acc[4]+=a1.x*w;  acc[5]+=a1.y*w;  acc[6]+=a1.z*w;  acc[7]+=a1.w*w;
    acc[8]+=a2.x*w;  acc[9]+=a2.y*w;  acc[10]+=a2.z*w; acc[11]+=a2.w*w;
    acc[12]+=a3.x*w; acc[13]+=a3.y*w; acc[14]+=a3.z*w; acc[15]+=a3.w*w;
    acc[16]+=a4.x*w; acc[17]+=a4.y*w; acc[18]+=a4.z*w; acc[19]+=a4.w*w;
    acc[20]+=a5.x*w; acc[21]+=a5.y*w; acc[22]+=a5.z*w; acc[23]+=a5.w*w;
    acc[24]+=a6*w;
}

// ================= BN branch, MFMA, 2 samples per block (proven) =================
__global__ __launch_bounds__(512,4) void bn_branch_mfma(
    const float* __restrict__ bottleneck, const float* __restrict__ pos,
    const float* __restrict__ dw_w, const float* __restrict__ dw_b,
    const float* __restrict__ ln_g, const float* __restrict__ ln_b,
    const float* __restrict__ pw1_b, const float* __restrict__ pw2_b,
    const float* __restrict__ cn_gamma, const float* __restrict__ bn1x1_b,
    const short8* __restrict__ P1v, const short8* __restrict__ P2v,
    const short8* __restrict__ Pbv,
    float* __restrict__ vec_out)
{
    __shared__ __align__(16) unsigned char Xb[64*512];   // 32KB
    __shared__ __align__(16) unsigned char Hc[64*256];   // 16KB
    __shared__ float redA[400], redB[400], muS[56], rsS[56];

    const int n0 = blockIdx.x*2, t = threadIdx.x;
    const int lane = t & 63, w = t >> 6;
    const int mcol = lane & 15, h4 = lane >> 4;
    const int sP = t >> 8, cP = t & 255;

    unsigned int wvp[13];
    float xdw[25];
    {
        const int n = n0 + sP;
        const float px = pos[2*n]*0.125f, py = pos[2*n+1]*0.125f;
        const float fpx = floorf(px), fpy = floorf(py);
        const int ix0 = (int)fpx - 2, iy0 = (int)fpy - 2;
        const float fx = px - fpx, fy = py - fpy;
        const float w00=(1.f-fy)*(1.f-fx), w01=(1.f-fy)*fx, w10=fy*(1.f-fx), w11=fy*fx;
        float wv[25];
        {
            const float* fm = bottleneck + cP*16384;
            float P[6][6];
            #pragma unroll
            for (int r=0;r<6;r++){
                const int y = iy0+r;
                const bool yok = (y>=0)&&(y<128);
                const int yc = y<0?0:(y>127?127:y);
                #pragma unroll
                for (int s=0;s<6;s++){
                    const int x = ix0+s;
                    const bool ok = yok && (x>=0) && (x<128);
                    const int xc = x<0?0:(x>127?127:x);
                    P[r][s] = ok ? fm[yc*128+xc] : 0.f;
                }
            }
            #pragma unroll
            for (int a=0;a<5;a++)
            #pragma unroll
            for (int b=0;b<5;b++)
                wv[a*5+b] = w00*P[a][b]+w01*P[a][b+1]+w10*P[a+1][b]+w11*P[a+1][b+1];
        }
        #pragma unroll
        for (int i=0;i<12;i++) wvp[i] = pack2(wv[2*i], wv[2*i+1]);
        wvp[12] = pack2(wv[24], 0.f);
        {
            float wcr[49];
            const float* wc = dw_w + cP*49;
            #pragma unroll
            for (int k=0;k<49;k++) wcr[k]=wc[k];
            const float bb = dw_b[cP];
            #pragma unroll
            for (int i=0;i<5;i++){
                #pragma unroll
                for (int j=0;j<5;j++){
                    float a = bb;
                    #pragma unroll
                    for (int u=0;u<7;u++){
                        const int y = i+u-3;
                        if (y<0||y>4) continue;
                        #pragma unroll
                        for (int v=0;v<7;v++){
                            const int x = j+v-3;
                            if (x<0||x>4) continue;
                            a += wv[y*5+x]*wcr[u*7+v];
                        }
                    }
                    xdw[i*5+j] = a;
                }
            }
        }
        #pragma unroll
        for (int p=0;p<25;p++){
            const int row = sP*32 + p;
            *(unsigned short*)(Xb + row*512 + ((2*cP) ^ ((row&7)<<4))) = f2bf(xdw[p]);
        }
    }
    __syncthreads();
    if (t < 400){
        const int sp = t>>3, part = t&7;
        const int row = (sp/25)*32 + (sp - (sp/25)*25);
        float a=0.f, b=0.f;
        for (int c=part; c<256; c+=8){
            const float v = bfu(*(const unsigned short*)(Xb + row*512 + ((2*c) ^ ((row&7)<<4))));
            a += v; b += v*v;
        }
        redA[t]=a; redB[t]=b;
    }
    __syncthreads();
    if (t < 50){
        float a=0.f, b=0.f;
        #pragma unroll
        for (int s=0;s<8;s++){ a+=redA[t*8+s]; b+=redB[t*8+s]; }
        const float m = a*(1.f/256.f);
        const float var = b*(1.f/256.f) - m*m;
        muS[t]=m; rsS[t]=rsqrtf(var+1e-6f);
    }
    __syncthreads();
    {
        const float g = ln_g[cP], bb = ln_b[cP];
        #pragma unroll
        for (int p=0;p<25;p++){
            const int row = sP*32 + p;
            const float v = (xdw[p]-muS[sP*25+p])*rsS[sP*25+p]*g + bb;
            *(unsigned short*)(Xb + row*512 + ((2*cP) ^ ((row&7)<<4))) = f2bf(v);
        }
    }
    __syncthreads();

    f32x4 acc2[2][4];
    #pragma unroll
    for (int ml=0;ml<2;ml++)
        #pragma unroll
        for (int nt=0;nt<4;nt++) acc2[ml][nt]=0.f;

    for (int ch=0; ch<8; ++ch){
        const int mt = ch*8 + w;
        f32x4 a1[4];
        #pragma unroll
        for (int nt=0;nt<4;nt++) a1[nt]=0.f;
        #pragma unroll
        for (int kk=0; kk<8; ++kk){
            const short8 av = P1v[((mt<<3)+kk)*64 + lane];
            #pragma unroll
            for (int nt=0; nt<4; ++nt){
                const int row = nt*16 + mcol;
                const int ad = row*512 + ((kk*64 + h4*16) ^ ((row&7)<<4));
                const short8 bv = *(const short8*)(Xb + ad);
                a1[nt] = __builtin_amdgcn_mfma_f32_16x16x32_bf16(av, bv, a1[nt], 0,0,0);
            }
        }
        {
            const float4 b1v = *(const float4*)(pw1_b + mt*16 + h4*4);
            #pragma unroll
            for (int nt=0; nt<4; ++nt){
                const int row = nt*16 + mcol;
                const float g0 = gelu_q(a1[nt].x + b1v.x);
                const float g1 = gelu_q(a1[nt].y + b1v.y);
                const float g2 = gelu_q(a1[nt].z + b1v.z);
                const float g3 = gelu_q(a1[nt].w + b1v.w);
                const int ad = row*256 + ((w*32 + h4*8) ^ ((row&7)<<4));
                *(uint2*)(Hc + ad) = make_uint2(pack2(g0,g1), pack2(g2,g3));
            }
        }
        __syncthreads();
        #pragma unroll
        for (int ml=0; ml<2; ++ml){
            const int mtc = w*2 + ml;
            #pragma unroll
            for (int kk2=0; kk2<4; ++kk2){
                const short8 av = P2v[(mtc*32 + (ch*4 + kk2))*64 + lane];
                #pragma unroll
                for (int nt=0; nt<4; ++nt){
                    const int row = nt*16 + mcol;
                    const int ad = row*256 + ((kk2*64 + h4*16) ^ ((row&7)<<4));
                    const short8 bv = *(const short8*)(Hc + ad);
                    acc2[ml][nt] = __builtin_amdgcn_mfma_f32_16x16x32_bf16(av, bv, acc2[ml][nt], 0,0,0);
                }
            }
        }
        __syncthreads();
    }

    #pragma unroll
    for (int ml=0; ml<2; ++ml){
        const int c0 = (w*2+ml)*16 + h4*4;
        const float4 gm = *(const float4*)(cn_gamma + c0);
        const float4 b2 = *(const float4*)(pw2_b + c0);
        #pragma unroll
        for (int nt=0; nt<4; ++nt){
            const int row = nt*16 + mcol;
            const int ad = row*512 + ((2*c0) ^ ((row&7)<<4));
            const float f0 = gm.x*(acc2[ml][nt].x + b2.x);
            const float f1 = gm.y*(acc2[ml][nt].y + b2.y);
            const float f2 = gm.z*(acc2[ml][nt].z + b2.z);
            const float f3 = gm.w*(acc2[ml][nt].w + b2.w);
            *(uint2*)(Xb + ad) = make_uint2(pack2(f0,f1), pack2(f2,f3));
        }
    }
    __syncthreads();
    #pragma unroll
    for (int p=0;p<25;p++){
        const int row = sP*32 + p;
        unsigned short* ptr = (unsigned short*)(Xb + row*512 + ((2*cP) ^ ((row&7)<<4)));
        const float r = (p&1) ? bf_hi(wvp[p>>1]) : bf_lo(wvp[p>>1]);
        *ptr = f2bf(bfu(*ptr) + r);
    }
    __syncthreads();

    {
        f32x4 a3[4];
        #pragma unroll
        for (int nt=0;nt<4;nt++) a3[nt]=0.f;
        #pragma unroll
        for (int kk=0; kk<8; ++kk){
            const short8 av = Pbv[((w<<3)+kk)*64 + lane];
            #pragma unroll
            for (int nt=0; nt<4; ++nt){
                const int row = nt*16 + mcol;
                const int ad = row*512 + ((kk*64 + h4*16) ^ ((row&7)<<4));
                const short8 bv = *(const short8*)(Xb + ad);
                a3[nt] = __builtin_amdgcn_mfma_f32_16x16x32_bf16(av, bv, a3[nt], 0,0,0);
            }
        }
        const float4 bb = *(const float4*)(bn1x1_b + w*16 + h4*4);
        float e5[5];
        #pragma unroll
        for (int a=0;a<5;a++){
            const float ta = -1.f + 0.5f*a;
            e5[a] = expf(-3.125f*ta*ta);
        }
        const float Sv = e5[0]+e5[1]+e5[2]+e5[3]+e5[4];
        const float invS = 1.0f/(Sv*Sv);
        float sA[2][4];
        #pragma unroll
        for (int s=0;s<2;s++)
            #pragma unroll
            for (int j=0;j<4;j++) sA[s][j]=0.f;
        #pragma unroll
        for (int nt=0; nt<4; ++nt){
            const int row = nt*16 + mcol;
            const int s = row>>5, p = row&31;
            if (p < 25){
                const int pa = p/5, pb = p - pa*5;
                const float g = e5[pa]*e5[pb];
                sA[s][0] += g*gelu_q(a3[nt].x + bb.x);
                sA[s][1] += g*gelu_q(a3[nt].y + bb.y);
                sA[s][2] += g*gelu_q(a3[nt].z + bb.z);
                sA[s][3] += g*gelu_q(a3[nt].w + bb.w);
            }
        }
        #pragma unroll
        for (int off=1; off<16; off<<=1){
            #pragma unroll
            for (int s=0;s<2;s++)
                #pragma unroll
                for (int j=0;j<4;j++) sA[s][j] += __shfl_xor(sA[s][j], off);
        }
        if (mcol == 0){
            const int o = w*16 + h4*4;
            #pragma unroll
            for (int s=0;s<2;s++){
                float* vo = vec_out + (n0+s)*192 + o;
                vo[0]=sA[s][0]*invS; vo[1]=sA[s][1]*invS;
                vo[2]=sA[s][2]*invS; vo[3]=sA[s][3]*invS;
            }
        }
    }
}

// ---- bn weight prepack (fixed bounds, proven) ----
__global__ __launch_bounds__(256) void prepack_bn_kernel(
    const float* __restrict__ W1, const float* __restrict__ W2, const float* __restrict__ Wb,
    unsigned short* __restrict__ P1, unsigned short* __restrict__ P2, unsigned short* __restrict__ Pb)
{
    const int tid = blockIdx.x*256 + threadIdx.x;
    const float* src; unsigned short* dst; int row, col, stride, idx;
    if (tid < 32768){
        idx = tid;
        const int frag = idx>>6, l = idx&63;
        row = (frag>>3)*16 + (l&15); col = (frag&7)*32 + (l>>4)*8; stride = 256;
        src = W1; dst = P1;
    } else if (tid < 65536){
        idx = tid - 32768;
        const int frag = idx>>6, l = idx&63;
        row = (frag>>5)*16 + (l&15); col = (frag&31)*32 + (l>>4)*8; stride = 1024;
        src = W2; dst = P2;
    } else if (tid < 69632){
        idx = tid - 65536;
        const int frag = idx>>6, l = idx&63;
        row = (frag>>3)*16 + (l&15); col = (frag&7)*32 + (l>>4)*8; stride = 256;
        src = Wb; dst = Pb;
    } else return;
    const float* s = src + row*stride + col;
    unsigned int v[4];
    #pragma unroll
    for (int j=0;j<4;j++) v[j] = pack2(s[2*j], s[2*j+1]);
    *(uint4*)(dst + (size_t)idx*8) = make_uint4(v[0],v[1],v[2],v[3]);
}

// ================= BN branch, VALU fallback (proven) =================
__global__ __launch_bounds__(256,2) void bn_branch_valu(
    const float* __restrict__ bottleneck, const float* __restrict__ pos,
    const float* __restrict__ dw_w, const float* __restrict__ dw_b,
    const float* __restrict__ ln_g, const float* __restrict__ ln_b,
    const float* __restrict__ pw1_w, const float* __restrict__ pw1_b,
    const float* __restrict__ pw2_w, const float* __restrict__ pw2_b,
    const float* __restrict__ cn_gamma,
    const float* __restrict__ bn1x1_w, const float* __restrict__ bn1x1_b,
    float* __restrict__ vec_out)
{
    __shared__ float xln[256*XSTR];
    __shared__ float hbuf[256*XSTR];
    __shared__ float redA[200], redB[200];
    __shared__ float mu[25], rs[25];

    const int n = blockIdx.x;
    const int t = threadIdx.x;
    const int c = t;

    const float px = pos[2*n]*0.125f, py = pos[2*n+1]*0.125f;
    const float fpx = floorf(px), fpy = floorf(py);
    const int ix0 = (int)fpx - 2, iy0 = (int)fpy - 2;
    const float fx = px - fpx, fy = py - fpy;
    const float w00=(1.f-fy)*(1.f-fx), w01=(1.f-fy)*fx, w10=fy*(1.f-fx), w11=fy*fx;

    float wv[25];
    {
        const float* fm = bottleneck + c*16384;
        float P[6][6];
        #pragma unroll
        for (int r=0;r<6;r++){
            const int y = iy0+r;
            const bool yok = (y>=0)&&(y<128);
            const int yc = y<0?0:(y>127?127:y);
            #pragma unroll
            for (int s=0;s<6;s++){
                const int x = ix0+s;
                const bool ok = yok && (x>=0) && (x<128);
                const int xc = x<0?0:(x>127?127:x);
                P[r][s] = ok ? fm[yc*128+xc] : 0.f;
            }
        }
        #pragma unroll
        for (int a=0;a<5;a++)
        #pragma unroll
        for (int b=0;b<5;b++)
            wv[a*5+b] = w00*P[a][b]+w01*P[a][b+1]+w10*P[a+1][b]+w11*P[a+1][b+1];
    }
    {
        float wcr[49];
        const float* wc = dw_w + c*49;
        #pragma unroll
        for (int k=0;k<49;k++) wcr[k]=wc[k];
        const float bb = dw_b[c];
        #pragma unroll
        for (int i=0;i<5;i++){
            #pragma unroll
            for (int j=0;j<5;j++){
                float a = bb;
                #pragma unroll
                for (int u=0;u<7;u++){
                    const int y = i+u-3;
                    if (y<0||y>4) continue;
                    #pragma unroll
                    for (int v=0;v<7;v++){
                        const int x = j+v-3;
                        if (x<0||x>4) continue;
                        a += wv[y*5+x]*wcr[u*7+v];
                    }
                }
                xln[c*XSTR + i*5+j] = a;
            }
        }
    }
    __syncthreads();
    if (t < 200){
        const int p = t>>3, s = t&7;
        float a=0.f, b=0.f;
        for (int cc=s; cc<256; cc+=8){
            const float v = xln[cc*XSTR+p];
            a += v; b += v*v;
        }
        redA[t]=a; redB[t]=b;
    }
    __syncthreads();
    if (t < 25){
        float a=0.f, b=0.f;
        #pragma unroll
        for (int s=0;s<8;s++){ a+=redA[t*8+s]; b+=redB[t*8+s]; }
        const float m = a*(1.f/256.f);
        const float var = b*(1.f/256.f) - m*m;
        mu[t]=m; rs[t]=rsqrtf(var+1e-6f);
    }
    __syncthreads();
    {
        const float g = ln_g[c], bb = ln_b[c];
        #pragma unroll
        for (int p=0;p<25;p++)
            xln[c*XSTR+p] = (xln[c*XSTR+p]-mu[p])*rs[p]*g + bb;
    }
    __syncthreads();
    float acc2[25];
    #pragma unroll
    for (int p=0;p<25;p++) acc2[p]=0.f;
    for (int r=0;r<4;r++){
        const int o = r*256 + t;
        float h[25];
        {
            const float b1 = pw1_b[o];
            #pragma unroll
            for (int p=0;p<25;p++) h[p]=b1;
            const float* wr = pw1_w + o*256;
            for (int cc=0;cc<256;cc++)
                fma_row25(xln + cc*XSTR, wr[cc], h);
            #pragma unroll
            for (int p=0;p<25;p++) h[p]=gelu_f(h[p]);
        }
        __syncthreads();
        #pragma unroll
        for (int p=0;p<25;p++) hbuf[t*XSTR+p]=h[p];
        __syncthreads();
        {
            const float* w2 = pw2_w + t*1024 + r*256;
            for (int k=0;k<256;k++)
                fma_row25(hbuf + k*XSTR, w2[k], acc2);
        }
    }
    {
        const float gam = cn_gamma[c], b2 = pw2_b[c];
        #pragma unroll
        for (int p=0;p<25;p++)
            xln[c*XSTR+p] = wv[p] + gam*(acc2[p]+b2);
    }
    __syncthreads();
    if (t < 128){
        float acc[25];
        #pragma unroll
        for (int p=0;p<25;p++) acc[p]=0.f;
        const float* wr = bn1x1_w + t*256;
        for (int cc=0;cc<256;cc++)
            fma_row25(xln + cc*XSTR, wr[cc], acc);
        const float b = bn1x1_b[t];
        float e5[5];
        #pragma unroll
        for (int a=0;a<5;a++){
            const float ta = -1.f + 0.5f*a;
            e5[a] = expf(-3.125f*ta*ta);
        }
        const float Sv = e5[0]+e5[1]+e5[2]+e5[3]+e5[4];
        float res = 0.f;
        #pragma unroll
        for (int a=0;a<5;a++){
            float rowa = 0.f;
            #pragma unroll
            for (int bb=0;bb<5;bb++)
                rowa += e5[bb]*gelu_f(acc[a*5+bb]+b);
            res += e5[a]*rowa;
        }
        vec_out[n*192+t] = res/(Sv*Sv);
    }
}

// ---------------- Stem weight prepack (unchanged, proven) ----------------
__global__ __launch_bounds__(256) void prepack_kernel(
    const float* __restrict__ W1, const float* __restrict__ W2,
    unsigned short* __restrict__ Ap)
{
    const int tid = blockIdx.x*256 + threadIdx.x;
    if (tid >= 9216) return;
    int r = tid;
    const int conv = r / 4608; r -= conv*4608;
    const int k = r / 512;     r -= k*512;
    const int s = r / 256;     r -= s*256;
    const int w = r / 64;
    const int l = r - w*64;
    const float* W = conv ? W2 : W1;
    const int o  = w*16 + (l & 15);
    const int c0 = s*32 + (l >> 4)*8;
    unsigned int v[4];
    #pragma unroll
    for (int jj=0; jj<4; jj++){
        const float f0 = W[o*576 + (c0+2*jj  )*9 + k];
        const float f1 = W[o*576 + (c0+2*jj+1)*9 + k];
        v[jj] = pack2(f0, f1);
    }
    uint4* dst = (uint4*)(Ap + (size_t)tid*8);
    *dst = make_uint4(v[0], v[1], v[2], v[3]);
}

// ---------------- Stem branch: MFMA + LDS address table ----------------
// Buffers: 290 rows x 128B (row 289 = zeros). sTab[m][nt*9+k] = pp*128 + ((pp&7)<<4) (u16).
// Per MFMA pair: ad0 = adh ^ (h*16); ad1 = ad0 ^ 64.
#define STEM_CONV_T(SRC, AP)                                                        \
    for (int k=0;k<9;k++){                                                          \
        const short8 a0 = (AP)[k*512       + w*64 + lane];                          \
        const short8 a1 = (AP)[k*512 + 256 + w*64 + lane];                          \
        const unsigned short* trow = sTab + m*171 + k;                              \
        _Pragma("unroll")                                                           \
        for (int nt=0; nt<19; nt++){                                                \
            const int ad0 = ((int)trow[nt*9]) ^ h16;                                \
            const short8 bv0 = *(const short8*)((SRC) + ad0);                       \
            acc[nt] = __builtin_amdgcn_mfma_f32_16x16x32_bf16(a0, bv0, acc[nt], 0,0,0); \
            const short8 bv1 = *(const short8*)((SRC) + (ad0 ^ 64));                \
            acc[nt] = __builtin_amdgcn_mfma_f32_16x16x32_bf16(a1, bv1, acc[nt], 0,0,0); \
        }                                                                           \
    }

__global__ __launch_bounds__(256,2) void stem_branch_kernel(
    const float* __restrict__ vis,
    const float* __restrict__ pos,
    const short8* __restrict__ Ap1,
    const float* __restrict__ st1_b,
    const float* __restrict__ st2_b,
    float* __restrict__ vec_out)
{
    __shared__ __align__(16) unsigned char sXt[290*128];   // 37120 B
    __shared__ __align__(16) unsigned char sC1[290*128];   // 37120 B
    __shared__ unsigned short sTab[16*171];                // 5472 B
    __shared__ float redS[64];

    const int n = blockIdx.x;
    const int t = threadIdx.x;
    const int lane = t & 63;
    const int m = t & 15;
    const int h16 = ((t >> 4) & 3) * 16;
    const int w = t >> 6;

    const float fpx0 = pos[2*n], fpy0 = pos[2*n+1];
    const float fpx = floorf(fpx0), fpy = floorf(fpy0);
    const int ix0 = (int)fpx - 8, iy0 = (int)fpy - 8;
    const float fx = fpx0-fpx, fy = fpy0-fpy;
    const float w00=(1.f-fy)*(1.f-fx), w01=(1.f-fy)*fx, w10=fy*(1.f-fx), w11=fy*fx;

    // zero row 289 of both buffers
    if (t < 32)      *(unsigned int*)(sXt + 289*128 + t*4) = 0u;
    else if (t < 64) *(unsigned int*)(sC1 + 289*128 + (t-32)*4) = 0u;

    // build address table: 2736 entries
    for (int idx = t; idx < 16*171; idx += 256){
        const int mm = idx/171, rem = idx - mm*171;
        const int nt = rem/9, k = rem - nt*9;
        const int p = nt*16 + mm;
        const int py = (p*241)>>12, px = p - py*17;
        const int dyy = k/3 - 1, dxx = k - (k/3)*3 - 1;
        const int y = py+dyy, x = px+dxx;
        const bool ok = ((unsigned)y < 17u) && ((unsigned)x < 17u);
        const int pp = ok ? (y*17+x) : 289;
        sTab[idx] = (unsigned short)(pp*128 + ((pp&7)<<4));
    }

    // gather + blend 17x17 windows -> sXt[p][c] bf16 (swizzled)
    for (int task = t; task < 64*17; task += 256){
        const int c  = task & 63;
        const int py = task >> 6;
        const float* r0 = vis + c*1048576 + (iy0+py)*1024 + ix0;
        float a[18], b[18];
        #pragma unroll
        for (int kk=0; kk<18; kk++){ a[kk]=r0[kk]; b[kk]=r0[1024+kk]; }
        #pragma unroll
        for (int px=0; px<17; px++){
            const float v = w00*a[px] + w01*a[px+1] + w10*b[px] + w11*b[px+1];
            const int p = py*17 + px;
            *(unsigned short*)(sXt + p*128 + ((2*c) ^ ((p&7)<<4))) = f2bf(v);
        }
    }
    __syncthreads();

    // ---- conv1 ----
    f32x4 acc[19];
    #pragma unroll
    for (int nt=0; nt<19; nt++) acc[nt] = 0.f;
    STEM_CONV_T(sXt, Ap1)

    {
        const int obase = w*16 + (h16>>2);   // w*16 + h*4
        const float bo0 = st1_b[obase], bo1 = st1_b[obase+1];
        const float bo2 = st1_b[obase+2], bo3 = st1_b[obase+3];
        #pragma unroll
        for (int nt=0; nt<19; nt++){
            const int p = nt*16 + m;
            if (p < 289){   // must not touch zero row 289
                const unsigned r01 = pack2(gelu_q(acc[nt].x+bo0), gelu_q(acc[nt].y+bo1));
                const unsigned r23 = pack2(gelu_q(acc[nt].z+bo2), gelu_q(acc[nt].w+bo3));
                const int ad = p*128 + ((2*obase) ^ ((p&7)<<4));
                *(uint2*)(sC1 + ad) = make_uint2(r01, r23);
            }
        }
    }
    __syncthreads();

    // ---- conv2 + gelu + gauss ----
    const short8* Ap2 = Ap1 + 4608;
    #pragma unroll
    for (int nt=0; nt<19; nt++) acc[nt] = 0.f;
    STEM_CONV_T(sC1, Ap2)

    {
        const int obase = w*16 + (h16>>2);
        const float bo0 = st2_b[obase], bo1 = st2_b[obase+1];
        const float bo2 = st2_b[obase+2], bo3 = st2_b[obase+3];
        float s0=0.f, s1=0.f, s2=0.f, s3=0.f;
        #pragma unroll
        for (int nt=0; nt<19; nt++){
            const int p = nt*16 + m;
            if (p < 289){
                const int py = (p*241)>>12;
                const int px = p - py*17;
                const float ty = -1.f + 0.125f*py;
                const float tx = -1.f + 0.125f*px;
                const float g = expf(-3.125f*(ty*ty + tx*tx));
                s0 += g*gelu_q(acc[nt].x+bo0);
                s1 += g*gelu_q(acc[nt].y+bo1);
                s2 += g*gelu_q(acc[nt].z+bo2);
                s3 += g*gelu_q(acc[nt].w+bo3);
            }
        }
        #pragma unroll
        for (int off=1; off<16; off<<=1){
            s0 += __shfl_xor(s0, off);
            s1 += __shfl_xor(s1, off);
            s2 += __shfl_xor(s2, off);
            s3 += __shfl_xor(s3, off);
        }
        if (m == 0){
            redS[obase]   = s0;
            redS[obase+1] = s1;
            redS[obase+2] = s2;
            redS[obase+3] = s3;
        }
    }
    __syncthreads();
    if (t < 64){
        float Sv = 0.f;
        #pragma unroll
        for (int j=0;j<17;j++){
            const float tj = -1.f + 0.125f*j;
            Sv += expf(-3.125f*tj*tj);
        }
        vec_out[n*192+128+t] = redS[t] / (Sv*Sv);
    }
}

// ---------------- Head: 16 samples/block (proven) ----------------
__global__ __launch_bounds__(128) void head16_kernel(
    const float* __restrict__ vec, const float* __restrict__ p2s,
    const float* __restrict__ h1_w, const float* __restrict__ h1_b,
    const float* __restrict__ h2_w, const float* __restrict__ h2_b,
    const float* __restrict__ h3_w, const float* __restrict__ h3_b,
    float* __restrict__ out, int N)
{
    __shared__ float v[16][192];
    __shared__ float x1s[16][132];
    __shared__ float x2s[16][132];
    __shared__ float o3s[16][4];
    const int n0 = blockIdx.x*16, t = threadIdx.x;

    for (int idx=t; idx<16*192; idx+=128){
        const int s = idx/192, k = idx - s*192;
        v[s][k] = vec[n0*192 + idx];
    }
    __syncthreads();
    {
        const int o = t;
        float acc[16];
        const float b = h1_b[o];
        #pragma unroll
        for (int s=0;s<16;s++) acc[s]=b;
        const float4* wr = (const float4*)(h1_w + o*192);
        for (int k4=0;k4<48;k4++){
            const float4 wv4 = wr[k4];
            #pragma unroll
            for (int s=0;s<16;s++){
                const float4 vv = *(const float4*)&v[s][k4*4];
                acc[s] += wv4.x*vv.x + wv4.y*vv.y + wv4.z*vv.z + wv4.w*vv.w;
            }
        }
        #pragma unroll
        for (int s=0;s<16;s++) x1s[s][o] = gelu_f(acc[s]);
    }
    __syncthreads();
    {
        const int o = t;
        float acc[16];
        const float b = h2_b[o];
        #pragma unroll
        for (int s=0;s<16;s++) acc[s]=b;
        const float4* wr = (const float4*)(h2_w + o*128);
        for (int k4=0;k4<32;k4++){
            const float4 wv4 = wr[k4];
            #pragma unroll
            for (int s=0;s<16;s++){
                const float4 vv = *(const float4*)&x1s[s][k4*4];
                acc[s] += wv4.x*vv.x + wv4.y*vv.y + wv4.z*vv.z + wv4.w*vv.w;
            }
        }
        #pragma unroll
        for (int s=0;s<16;s++) x2s[s][o] = gelu_f(acc[s]);
    }
    __syncthreads();
    if (t < 48){
        const int j = t>>4, s = t&15;
        float a = h3_b[j];
        const float* wr = h3_w + j*128;
        for (int k=0;k<128;k++) a += x2s[s][k]*wr[k];
        o3s[s][j] = a;
    }
    __syncthreads();
    if (t < 16){
        const int s = t, n = n0 + s;
        const float dx = o3s[s][0], dy = o3s[s][1];
        float ls = o3s[s][2];
        ls = ls < -6.f ? -6.f : (ls > 3.f ? 3.f : ls);
        const float s0 = p2s[n*4+0]*dx + p2s[n*4+1]*dy;
        const float s1 = p2s[n*4+2]*dx + p2s[n*4+3]*dy;
        const float conf = 1.0f/fmaxf(expf(ls), 1e-4f);
        out[2*n]   = s0;
        out[2*n+1] = s1;
        out[2*N+n] = dx;
        out[3*N+n] = dy;
        out[4*N+n] = ls;
        out[5*N+n] = conf;
    }
}

extern "C" void kernel_launch(void* const* d_in, const int* in_sizes, int n_in,
                              void* d_out, int out_size, void* d_ws, size_t ws_size,
                              hipStream_t stream)
{
    (void)n_in; (void)out_size;
    const float* bottleneck = (const float*)d_in[0];
    const float* vis        = (const float*)d_in[1];
    const float* pos        = (const float*)d_in[2];
    const float* p2s        = (const float*)d_in[3];
    const float* dw_w  = (const float*)d_in[8];
    const float* dw_b  = (const float*)d_in[9];
    const float* ln_g  = (const float*)d_in[10];
    const float* ln_b  = (const float*)d_in[11];
    const float* pw1_w = (const float*)d_in[12];
    const float* pw1_b = (const float*)d_in[13];
    const float* pw2_w = (const float*)d_in[14];
    const float* pw2_b = (const float*)d_in[15];
    const float* gam   = (const float*)d_in[16];
    const float* b1w   = (const float*)d_in[17];
    const float* b1b   = (const float*)d_in[18];
    const float* s1w   = (const float*)d_in[19];
    const float* s1b   = (const float*)d_in[20];
    const float* s2w   = (const float*)d_in[21];
    const float* s2b   = (const float*)d_in[22];
    const float* h1w   = (const float*)d_in[23];
    const float* h1b   = (const float*)d_in[24];
    const float* h2w   = (const float*)d_in[25];
    const float* h2b   = (const float*)d_in[26];
    const float* h3w   = (const float*)d_in[27];
    const float* h3b   = (const float*)d_in[28];

    const int N = in_sizes[2]/2;            // 4096
    float* vec = (float*)d_ws;              // [N][192] f32
    const size_t vec_bytes = (size_t)N*192*sizeof(float);
    unsigned short* Apack = (unsigned short*)((char*)d_ws + vec_bytes);  // stem: 147456 B
    unsigned short* P1 = Apack + 73728;
    unsigned short* P2 = P1 + 262144;
    unsigned short* Pb = P2 + 262144;
    const size_t need = vec_bytes + 147456u + (262144u+262144u+32768u)*2u;

    hipMemsetAsync(d_ws, 0, vec_bytes, stream);

    prepack_kernel<<<36, 256, 0, stream>>>(s1w, s2w, Apack);

    if (ws_size >= need){
        prepack_bn_kernel<<<272, 256, 0, stream>>>(pw1_w, pw2_w, b1w, P1, P2, Pb);
        bn_branch_mfma<<<N/2, 512, 0, stream>>>(bottleneck, pos, dw_w, dw_b, ln_g, ln_b,
                                                pw1_b, pw2_b, gam, b1b,
                                                (const short8*)P1, (const short8*)P2, (const short8*)Pb,
                                                vec);
    } else {
        bn_branch_valu<<<N, 256, 0, stream>>>(bottleneck, pos, dw_w, dw_b, ln_g, ln_b,
                                              pw1_w, pw1_b, pw2_w, pw2_b, gam, b1w, b1b, vec);
    }
    stem_branch_kernel<<<N, 256, 0, stream>>>(vis, pos, (const short8*)Apack, s1b, s2b, vec);
    head16_kernel<<<N/16, 128, 0, stream>>>(vec, p2s, h1w, h1b, h2w, h2b, h3w, h3b,
                                            (float*)d_out, N);
}

// Round 9
// 824.755 us; speedup vs baseline: 24.5507x; 1.0500x over previous
//
#include <hip/hip_runtime.h>
#include <hip/hip_bf16.h>

#define XSTR 28   // legacy BN VALU kernel stride

typedef short short8 __attribute__((ext_vector_type(8)));
typedef float f32x4  __attribute__((ext_vector_type(4)));
typedef float f32x16 __attribute__((ext_vector_type(16)));

__device__ __forceinline__ float gelu_f(float x){
    return 0.5f*x*(1.0f + erff(x*0.70710678118654752f));
}
// fast gelu, tanh form: x*sigmoid(1.5958(x+0.044715x^3)), |err| <= ~3e-4
__device__ __forceinline__ float gelu_q(float x){
    const float z = 1.5957691216057308f*x*(1.0f + 0.044715f*x*x);
    return x / (1.0f + __expf(-z));
}
__device__ __forceinline__ unsigned short f2bf(float f){
    unsigned int u = __float_as_uint(f);
    u += 0x7fffu + ((u>>16)&1u);
    return (unsigned short)(u>>16);
}
__device__ __forceinline__ unsigned int pack2(float a, float b){
    return (unsigned int)f2bf(a) | ((unsigned int)f2bf(b)<<16);
}
__device__ __forceinline__ float bf_lo(unsigned int u){ return __uint_as_float(u<<16); }
__device__ __forceinline__ float bf_hi(unsigned int u){ return __uint_as_float(u & 0xffff0000u); }
__device__ __forceinline__ float bfu(unsigned short v){ return __uint_as_float(((unsigned int)v)<<16); }

__device__ __forceinline__ void fma_row25(const float* __restrict__ row, float w, float* __restrict__ acc){
    const float4* r4 = (const float4*)row;
    float4 a0=r4[0], a1=r4[1], a2=r4[2], a3=r4[3], a4=r4[4], a5=r4[5];
    float a6 = row[24];
    acc[0]+=a0.x*w;  acc[1]+=a0.y*w;  acc[2]+=a0.z*w;  acc[3]+=a0.w*w;
    acc[4]+=a1.x*w;  acc[5]+=a1.y*w;  acc[6]+=a1.z*w;  acc[7]+=a1.w*w;
    acc[8]+=a2.x*w;  acc[9]+=a2.y*w;  acc[10]+=a2.z*w; acc[11]+=a2.w*w;
    acc[12]+=a3.x*w; acc[13]+=a3.y*w; acc[14]+=a3.z*w; acc[15]+=a3.w*w;
    acc[16]+=a4.x*w; acc[17]+=a4.y*w; acc[18]+=a4.z*w; acc[19]+=a4.w*w;
    acc[20]+=a5.x*w; acc[21]+=a5.y*w; acc[22]+=a5.z*w; acc[23]+=a5.w*w;
    acc[24]+=a6*w;
}

// ================= BN branch, MFMA, 2 samples per block (proven r7/r8) =================
__global__ __launch_bounds__(512,4) void bn_branch_mfma(
    const float* __restrict__ bottleneck, const float* __restrict__ pos,
    const float* __restrict__ dw_w, const float* __restrict__ dw_b,
    const float* __restrict__ ln_g, const float* __restrict__ ln_b,
    const float* __restrict__ pw1_b, const float* __restrict__ pw2_b,
    const float* __restrict__ cn_gamma, const float* __restrict__ bn1x1_b,
    const short8* __restrict__ P1v, const short8* __restrict__ P2v,
    const short8* __restrict__ Pbv,
    float* __restrict__ vec_out)
{
    __shared__ __align__(16) unsigned char Xb[64*512];
    __shared__ __align__(16) unsigned char Hc[64*256];
    __shared__ float redA[400], redB[400], muS[56], rsS[56];

    const int n0 = blockIdx.x*2, t = threadIdx.x;
    const int lane = t & 63, w = t >> 6;
    const int mcol = lane & 15, h4 = lane >> 4;
    const int sP = t >> 8, cP = t & 255;

    unsigned int wvp[13];
    float xdw[25];
    {
        const int n = n0 + sP;
        const float px = pos[2*n]*0.125f, py = pos[2*n+1]*0.125f;
        const float fpx = floorf(px), fpy = floorf(py);
        const int ix0 = (int)fpx - 2, iy0 = (int)fpy - 2;
        const float fx = px - fpx, fy = py - fpy;
        const float w00=(1.f-fy)*(1.f-fx), w01=(1.f-fy)*fx, w10=fy*(1.f-fx), w11=fy*fx;
        float wv[25];
        {
            const float* fm = bottleneck + cP*16384;
            float P[6][6];
            #pragma unroll
            for (int r=0;r<6;r++){
                const int y = iy0+r;
                const bool yok = (y>=0)&&(y<128);
                const int yc = y<0?0:(y>127?127:y);
                #pragma unroll
                for (int s=0;s<6;s++){
                    const int x = ix0+s;
                    const bool ok = yok && (x>=0) && (x<128);
                    const int xc = x<0?0:(x>127?127:x);
                    P[r][s] = ok ? fm[yc*128+xc] : 0.f;
                }
            }
            #pragma unroll
            for (int a=0;a<5;a++)
            #pragma unroll
            for (int b=0;b<5;b++)
                wv[a*5+b] = w00*P[a][b]+w01*P[a][b+1]+w10*P[a+1][b]+w11*P[a+1][b+1];
        }
        #pragma unroll
        for (int i=0;i<12;i++) wvp[i] = pack2(wv[2*i], wv[2*i+1]);
        wvp[12] = pack2(wv[24], 0.f);
        {
            float wcr[49];
            const float* wc = dw_w + cP*49;
            #pragma unroll
            for (int k=0;k<49;k++) wcr[k]=wc[k];
            const float bb = dw_b[cP];
            #pragma unroll
            for (int i=0;i<5;i++){
                #pragma unroll
                for (int j=0;j<5;j++){
                    float a = bb;
                    #pragma unroll
                    for (int u=0;u<7;u++){
                        const int y = i+u-3;
                        if (y<0||y>4) continue;
                        #pragma unroll
                        for (int v=0;v<7;v++){
                            const int x = j+v-3;
                            if (x<0||x>4) continue;
                            a += wv[y*5+x]*wcr[u*7+v];
                        }
                    }
                    xdw[i*5+j] = a;
                }
            }
        }
        #pragma unroll
        for (int p=0;p<25;p++){
            const int row = sP*32 + p;
            *(unsigned short*)(Xb + row*512 + ((2*cP) ^ ((row&7)<<4))) = f2bf(xdw[p]);
        }
    }
    __syncthreads();
    if (t < 400){
        const int sp = t>>3, part = t&7;
        const int row = (sp/25)*32 + (sp - (sp/25)*25);
        float a=0.f, b=0.f;
        for (int c=part; c<256; c+=8){
            const float v = bfu(*(const unsigned short*)(Xb + row*512 + ((2*c) ^ ((row&7)<<4))));
            a += v; b += v*v;
        }
        redA[t]=a; redB[t]=b;
    }
    __syncthreads();
    if (t < 50){
        float a=0.f, b=0.f;
        #pragma unroll
        for (int s=0;s<8;s++){ a+=redA[t*8+s]; b+=redB[t*8+s]; }
        const float m = a*(1.f/256.f);
        const float var = b*(1.f/256.f) - m*m;
        muS[t]=m; rsS[t]=rsqrtf(var+1e-6f);
    }
    __syncthreads();
    {
        const float g = ln_g[cP], bb = ln_b[cP];
        #pragma unroll
        for (int p=0;p<25;p++){
            const int row = sP*32 + p;
            const float v = (xdw[p]-muS[sP*25+p])*rsS[sP*25+p]*g + bb;
            *(unsigned short*)(Xb + row*512 + ((2*cP) ^ ((row&7)<<4))) = f2bf(v);
        }
    }
    __syncthreads();

    f32x4 acc2[2][4];
    #pragma unroll
    for (int ml=0;ml<2;ml++)
        #pragma unroll
        for (int nt=0;nt<4;nt++) acc2[ml][nt]=0.f;

    for (int ch=0; ch<8; ++ch){
        const int mt = ch*8 + w;
        f32x4 a1[4];
        #pragma unroll
        for (int nt=0;nt<4;nt++) a1[nt]=0.f;
        #pragma unroll
        for (int kk=0; kk<8; ++kk){
            const short8 av = P1v[((mt<<3)+kk)*64 + lane];
            #pragma unroll
            for (int nt=0; nt<4; ++nt){
                const int row = nt*16 + mcol;
                const int ad = row*512 + ((kk*64 + h4*16) ^ ((row&7)<<4));
                const short8 bv = *(const short8*)(Xb + ad);
                a1[nt] = __builtin_amdgcn_mfma_f32_16x16x32_bf16(av, bv, a1[nt], 0,0,0);
            }
        }
        {
            const float4 b1v = *(const float4*)(pw1_b + mt*16 + h4*4);
            #pragma unroll
            for (int nt=0; nt<4; ++nt){
                const int row = nt*16 + mcol;
                const float g0 = gelu_q(a1[nt].x + b1v.x);
                const float g1 = gelu_q(a1[nt].y + b1v.y);
                const float g2 = gelu_q(a1[nt].z + b1v.z);
                const float g3 = gelu_q(a1[nt].w + b1v.w);
                const int ad = row*256 + ((w*32 + h4*8) ^ ((row&7)<<4));
                *(uint2*)(Hc + ad) = make_uint2(pack2(g0,g1), pack2(g2,g3));
            }
        }
        __syncthreads();
        #pragma unroll
        for (int ml=0; ml<2; ++ml){
            const int mtc = w*2 + ml;
            #pragma unroll
            for (int kk2=0; kk2<4; ++kk2){
                const short8 av = P2v[(mtc*32 + (ch*4 + kk2))*64 + lane];
                #pragma unroll
                for (int nt=0; nt<4; ++nt){
                    const int row = nt*16 + mcol;
                    const int ad = row*256 + ((kk2*64 + h4*16) ^ ((row&7)<<4));
                    const short8 bv = *(const short8*)(Hc + ad);
                    acc2[ml][nt] = __builtin_amdgcn_mfma_f32_16x16x32_bf16(av, bv, acc2[ml][nt], 0,0,0);
                }
            }
        }
        __syncthreads();
    }

    #pragma unroll
    for (int ml=0; ml<2; ++ml){
        const int c0 = (w*2+ml)*16 + h4*4;
        const float4 gm = *(const float4*)(cn_gamma + c0);
        const float4 b2 = *(const float4*)(pw2_b + c0);
        #pragma unroll
        for (int nt=0; nt<4; ++nt){
            const int row = nt*16 + mcol;
            const int ad = row*512 + ((2*c0) ^ ((row&7)<<4));
            const float f0 = gm.x*(acc2[ml][nt].x + b2.x);
            const float f1 = gm.y*(acc2[ml][nt].y + b2.y);
            const float f2 = gm.z*(acc2[ml][nt].z + b2.z);
            const float f3 = gm.w*(acc2[ml][nt].w + b2.w);
            *(uint2*)(Xb + ad) = make_uint2(pack2(f0,f1), pack2(f2,f3));
        }
    }
    __syncthreads();
    #pragma unroll
    for (int p=0;p<25;p++){
        const int row = sP*32 + p;
        unsigned short* ptr = (unsigned short*)(Xb + row*512 + ((2*cP) ^ ((row&7)<<4)));
        const float r = (p&1) ? bf_hi(wvp[p>>1]) : bf_lo(wvp[p>>1]);
        *ptr = f2bf(bfu(*ptr) + r);
    }
    __syncthreads();

    {
        f32x4 a3[4];
        #pragma unroll
        for (int nt=0;nt<4;nt++) a3[nt]=0.f;
        #pragma unroll
        for (int kk=0; kk<8; ++kk){
            const short8 av = Pbv[((w<<3)+kk)*64 + lane];
            #pragma unroll
            for (int nt=0; nt<4; ++nt){
                const int row = nt*16 + mcol;
                const int ad = row*512 + ((kk*64 + h4*16) ^ ((row&7)<<4));
                const short8 bv = *(const short8*)(Xb + ad);
                a3[nt] = __builtin_amdgcn_mfma_f32_16x16x32_bf16(av, bv, a3[nt], 0,0,0);
            }
        }
        const float4 bb = *(const float4*)(bn1x1_b + w*16 + h4*4);
        float e5[5];
        #pragma unroll
        for (int a=0;a<5;a++){
            const float ta = -1.f + 0.5f*a;
            e5[a] = expf(-3.125f*ta*ta);
        }
        const float Sv = e5[0]+e5[1]+e5[2]+e5[3]+e5[4];
        const float invS = 1.0f/(Sv*Sv);
        float sA[2][4];
        #pragma unroll
        for (int s=0;s<2;s++)
            #pragma unroll
            for (int j=0;j<4;j++) sA[s][j]=0.f;
        #pragma unroll
        for (int nt=0; nt<4; ++nt){
            const int row = nt*16 + mcol;
            const int s = row>>5, p = row&31;
            if (p < 25){
                const int pa = p/5, pb = p - pa*5;
                const float g = e5[pa]*e5[pb];
                sA[s][0] += g*gelu_q(a3[nt].x + bb.x);
                sA[s][1] += g*gelu_q(a3[nt].y + bb.y);
                sA[s][2] += g*gelu_q(a3[nt].z + bb.z);
                sA[s][3] += g*gelu_q(a3[nt].w + bb.w);
            }
        }
        #pragma unroll
        for (int off=1; off<16; off<<=1){
            #pragma unroll
            for (int s=0;s<2;s++)
                #pragma unroll
                for (int j=0;j<4;j++) sA[s][j] += __shfl_xor(sA[s][j], off);
        }
        if (mcol == 0){
            const int o = w*16 + h4*4;
            #pragma unroll
            for (int s=0;s<2;s++){
                float* vo = vec_out + (n0+s)*192 + o;
                vo[0]=sA[s][0]*invS; vo[1]=sA[s][1]*invS;
                vo[2]=sA[s][2]*invS; vo[3]=sA[s][3]*invS;
            }
        }
    }
}

// ---- bn weight prepack (proven) ----
__global__ __launch_bounds__(256) void prepack_bn_kernel(
    const float* __restrict__ W1, const float* __restrict__ W2, const float* __restrict__ Wb,
    unsigned short* __restrict__ P1, unsigned short* __restrict__ P2, unsigned short* __restrict__ Pb)
{
    const int tid = blockIdx.x*256 + threadIdx.x;
    const float* src; unsigned short* dst; int row, col, stride, idx;
    if (tid < 32768){
        idx = tid;
        const int frag = idx>>6, l = idx&63;
        row = (frag>>3)*16 + (l&15); col = (frag&7)*32 + (l>>4)*8; stride = 256;
        src = W1; dst = P1;
    } else if (tid < 65536){
        idx = tid - 32768;
        const int frag = idx>>6, l = idx&63;
        row = (frag>>5)*16 + (l&15); col = (frag&31)*32 + (l>>4)*8; stride = 1024;
        src = W2; dst = P2;
    } else if (tid < 69632){
        idx = tid - 65536;
        const int frag = idx>>6, l = idx&63;
        row = (frag>>3)*16 + (l&15); col = (frag&7)*32 + (l>>4)*8; stride = 256;
        src = Wb; dst = Pb;
    } else return;
    const float* s = src + row*stride + col;
    unsigned int v[4];
    #pragma unroll
    for (int j=0;j<4;j++) v[j] = pack2(s[2*j], s[2*j+1]);
    *(uint4*)(dst + (size_t)idx*8) = make_uint4(v[0],v[1],v[2],v[3]);
}

// ================= BN branch, VALU fallback (proven) =================
__global__ __launch_bounds__(256,2) void bn_branch_valu(
    const float* __restrict__ bottleneck, const float* __restrict__ pos,
    const float* __restrict__ dw_w, const float* __restrict__ dw_b,
    const float* __restrict__ ln_g, const float* __restrict__ ln_b,
    const float* __restrict__ pw1_w, const float* __restrict__ pw1_b,
    const float* __restrict__ pw2_w, const float* __restrict__ pw2_b,
    const float* __restrict__ cn_gamma,
    const float* __restrict__ bn1x1_w, const float* __restrict__ bn1x1_b,
    float* __restrict__ vec_out)
{
    __shared__ float xln[256*XSTR];
    __shared__ float hbuf[256*XSTR];
    __shared__ float redA[200], redB[200];
    __shared__ float mu[25], rs[25];

    const int n = blockIdx.x;
    const int t = threadIdx.x;
    const int c = t;

    const float px = pos[2*n]*0.125f, py = pos[2*n+1]*0.125f;
    const float fpx = floorf(px), fpy = floorf(py);
    const int ix0 = (int)fpx - 2, iy0 = (int)fpy - 2;
    const float fx = px - fpx, fy = py - fpy;
    const float w00=(1.f-fy)*(1.f-fx), w01=(1.f-fy)*fx, w10=fy*(1.f-fx), w11=fy*fx;

    float wv[25];
    {
        const float* fm = bottleneck + c*16384;
        float P[6][6];
        #pragma unroll
        for (int r=0;r<6;r++){
            const int y = iy0+r;
            const bool yok = (y>=0)&&(y<128);
            const int yc = y<0?0:(y>127?127:y);
            #pragma unroll
            for (int s=0;s<6;s++){
                const int x = ix0+s;
                const bool ok = yok && (x>=0) && (x<128);
                const int xc = x<0?0:(x>127?127:x);
                P[r][s] = ok ? fm[yc*128+xc] : 0.f;
            }
        }
        #pragma unroll
        for (int a=0;a<5;a++)
        #pragma unroll
        for (int b=0;b<5;b++)
            wv[a*5+b] = w00*P[a][b]+w01*P[a][b+1]+w10*P[a+1][b]+w11*P[a+1][b+1];
    }
    {
        float wcr[49];
        const float* wc = dw_w + c*49;
        #pragma unroll
        for (int k=0;k<49;k++) wcr[k]=wc[k];
        const float bb = dw_b[c];
        #pragma unroll
        for (int i=0;i<5;i++){
            #pragma unroll
            for (int j=0;j<5;j++){
                float a = bb;
                #pragma unroll
                for (int u=0;u<7;u++){
                    const int y = i+u-3;
                    if (y<0||y>4) continue;
                    #pragma unroll
                    for (int v=0;v<7;v++){
                        const int x = j+v-3;
                        if (x<0||x>4) continue;
                        a += wv[y*5+x]*wcr[u*7+v];
                    }
                }
                xln[c*XSTR + i*5+j] = a;
            }
        }
    }
    __syncthreads();
    if (t < 200){
        const int p = t>>3, s = t&7;
        float a=0.f, b=0.f;
        for (int cc=s; cc<256; cc+=8){
            const float v = xln[cc*XSTR+p];
            a += v; b += v*v;
        }
        redA[t]=a; redB[t]=b;
    }
    __syncthreads();
    if (t < 25){
        float a=0.f, b=0.f;
        #pragma unroll
        for (int s=0;s<8;s++){ a+=redA[t*8+s]; b+=redB[t*8+s]; }
        const float m = a*(1.f/256.f);
        const float var = b*(1.f/256.f) - m*m;
        mu[t]=m; rs[t]=rsqrtf(var+1e-6f);
    }
    __syncthreads();
    {
        const float g = ln_g[c], bb = ln_b[c];
        #pragma unroll
        for (int p=0;p<25;p++)
            xln[c*XSTR+p] = (xln[c*XSTR+p]-mu[p])*rs[p]*g + bb;
    }
    __syncthreads();
    float acc2[25];
    #pragma unroll
    for (int p=0;p<25;p++) acc2[p]=0.f;
    for (int r=0;r<4;r++){
        const int o = r*256 + t;
        float h[25];
        {
            const float b1 = pw1_b[o];
            #pragma unroll
            for (int p=0;p<25;p++) h[p]=b1;
            const float* wr = pw1_w + o*256;
            for (int cc=0;cc<256;cc++)
                fma_row25(xln + cc*XSTR, wr[cc], h);
            #pragma unroll
            for (int p=0;p<25;p++) h[p]=gelu_f(h[p]);
        }
        __syncthreads();
        #pragma unroll
        for (int p=0;p<25;p++) hbuf[t*XSTR+p]=h[p];
        __syncthreads();
        {
            const float* w2 = pw2_w + t*1024 + r*256;
            for (int k=0;k<256;k++)
                fma_row25(hbuf + k*XSTR, w2[k], acc2);
        }
    }
    {
        const float gam = cn_gamma[c], b2 = pw2_b[c];
        #pragma unroll
        for (int p=0;p<25;p++)
            xln[c*XSTR+p] = wv[p] + gam*(acc2[p]+b2);
    }
    __syncthreads();
    if (t < 128){
        float acc[25];
        #pragma unroll
        for (int p=0;p<25;p++) acc[p]=0.f;
        const float* wr = bn1x1_w + t*256;
        for (int cc=0;cc<256;cc++)
            fma_row25(xln + cc*XSTR, wr[cc], acc);
        const float b = bn1x1_b[t];
        float e5[5];
        #pragma unroll
        for (int a=0;a<5;a++){
            const float ta = -1.f + 0.5f*a;
            e5[a] = expf(-3.125f*ta*ta);
        }
        const float Sv = e5[0]+e5[1]+e5[2]+e5[3]+e5[4];
        float res = 0.f;
        #pragma unroll
        for (int a=0;a<5;a++){
            float rowa = 0.f;
            #pragma unroll
            for (int bb=0;bb<5;bb++)
                rowa += e5[bb]*gelu_f(acc[a*5+bb]+b);
            res += e5[a]*rowa;
        }
        vec_out[n*192+t] = res/(Sv*Sv);
    }
}

// ---------------- Stem weight prepack: 32x32x16 A-fragment layout ----------------
// frag = k*8 + kt*2 + wo ; value[lane][j] = W[o=wo*32+(lane&31)][c=kt*16+(lane>>5)*8+j][k]
__global__ __launch_bounds__(256) void prepack_kernel(
    const float* __restrict__ W1, const float* __restrict__ W2,
    unsigned short* __restrict__ Ap)
{
    const int tid = blockIdx.x*256 + threadIdx.x;
    if (tid >= 9216) return;
    const int conv = tid / 4608;
    const int r = tid - conv*4608;
    const int frag = r >> 6, l = r & 63;
    const int k  = frag >> 3;
    const int kt = (frag >> 1) & 3;
    const int wo = frag & 1;
    const float* W = conv ? W2 : W1;
    const int o  = wo*32 + (l & 31);
    const int c0 = kt*16 + (l >> 5)*8;
    unsigned int v[4];
    #pragma unroll
    for (int jj=0; jj<4; jj++){
        const float f0 = W[o*576 + (c0+2*jj  )*9 + k];
        const float f1 = W[o*576 + (c0+2*jj+1)*9 + k];
        v[jj] = pack2(f0, f1);
    }
    *(uint4*)(Ap + (size_t)tid*8) = make_uint4(v[0], v[1], v[2], v[3]);
}

// ---------------- Stem branch: 32x32x16 MFMA + LDS address table ----------------
// Buffers 290 rows x 128B (row 289 = zeros). sTab[m][nt*9+k] = pp*128 + ((pp&7)<<4).
// B read: ad = tab ^ (kt*32 + hi*16)  (tab bits 0-3 are zero; XOR = channel-group select).
#define STEM_CONV32(SRC, AP)                                                        \
    for (int k=0;k<9;k++){                                                          \
        const unsigned short* trow = sTab + m*90 + nh*45 + k;                       \
        int tj[5];                                                                  \
        _Pragma("unroll")                                                           \
        for (int j=0;j<5;j++) tj[j] = trow[j*9];                                    \
        _Pragma("unroll")                                                           \
        for (int kt=0;kt<4;kt++){                                                   \
            const short8 av = (AP)[(k*8 + kt*2 + wo)*64 + lane];                    \
            const int cb = kt*32 + hi16;                                            \
            _Pragma("unroll")                                                       \
            for (int j=0;j<5;j++){                                                  \
                const short8 bv = *(const short8*)((SRC) + (tj[j] ^ cb));           \
                acc[j] = __builtin_amdgcn_mfma_f32_32x32x16_bf16(av, bv, acc[j], 0,0,0); \
            }                                                                       \
        }                                                                           \
    }

__global__ __launch_bounds__(256,2) void stem_branch_kernel(
    const float* __restrict__ vis,
    const float* __restrict__ pos,
    const short8* __restrict__ Ap1,
    const float* __restrict__ st1_b,
    const float* __restrict__ st2_b,
    float* __restrict__ vec_out)
{
    __shared__ __align__(16) unsigned char sXt[290*128];   // 37120 B
    __shared__ __align__(16) unsigned char sC1[290*128];   // 37120 B
    __shared__ unsigned short sTab[32*90];                 // 5760 B
    __shared__ float redS[64][2];                          // 512 B

    const int n = blockIdx.x;
    const int t = threadIdx.x;
    const int lane = t & 63;
    const int m = lane & 31;          // MFMA col = position within N-tile
    const int hi = lane >> 5;         // K-group
    const int hi16 = hi*16;
    const int w = t >> 6;
    const int wo = w & 1;             // o-tile: channels wo*32..wo*32+31
    const int nh = w >> 1;            // N-half: tiles nh*5..nh*5+4

    const float fpx0 = pos[2*n], fpy0 = pos[2*n+1];
    const float fpx = floorf(fpx0), fpy = floorf(fpy0);
    const int ix0 = (int)fpx - 8, iy0 = (int)fpy - 8;
    const float fx = fpx0-fpx, fy = fpy0-fpy;
    const float w00=(1.f-fy)*(1.f-fx), w01=(1.f-fy)*fx, w10=fy*(1.f-fx), w11=fy*fx;

    // zero row 289 of both buffers
    if (t < 32)      *(unsigned int*)(sXt + 289*128 + t*4) = 0u;
    else if (t < 64) *(unsigned int*)(sC1 + 289*128 + (t-32)*4) = 0u;

    // address table: 32 m x 10 nt x 9 k
    for (int idx = t; idx < 32*90; idx += 256){
        const int mm = idx/90, rem = idx - mm*90;
        const int nt = rem/9, k = rem - nt*9;
        const int p = nt*32 + mm;
        int pp = 289;
        if (p < 289){
            const int py = (p*241)>>12, px = p - py*17;
            const int y = py + k/3 - 1, x = px + (k - (k/3)*3) - 1;
            if (((unsigned)y < 17u) && ((unsigned)x < 17u)) pp = y*17 + x;
        }
        sTab[idx] = (unsigned short)(pp*128 + ((pp&7)<<4));
    }

    // gather + blend 17x17 windows -> sXt[p][c] bf16 (swizzled)
    for (int task = t; task < 64*17; task += 256){
        const int c  = task & 63;
        const int py = task >> 6;
        const float* r0 = vis + c*1048576 + (iy0+py)*1024 + ix0;
        float a[18], b[18];
        #pragma unroll
        for (int kk=0; kk<18; kk++){ a[kk]=r0[kk]; b[kk]=r0[1024+kk]; }
        #pragma unroll
        for (int px=0; px<17; px++){
            const float v = w00*a[px] + w01*a[px+1] + w10*b[px] + w11*b[px+1];
            const int p = py*17 + px;
            *(unsigned short*)(sXt + p*128 + ((2*c) ^ ((p&7)<<4))) = f2bf(v);
        }
    }
    __syncthreads();

    // ---- conv1 ----
    f32x16 acc[5];
    #pragma unroll
    for (int j=0;j<5;j++) acc[j] = 0.f;
    STEM_CONV32(sXt, Ap1)

    {   // +bias, gelu, write c1[p][o] bf16 (swizzled); reg quad rg -> channels wo*32+8rg+4hi+(0..3)
        float4 b4[4];
        #pragma unroll
        for (int rg=0;rg<4;rg++) b4[rg] = *(const float4*)(st1_b + wo*32 + 8*rg + 4*hi);
        #pragma unroll
        for (int j=0;j<5;j++){
            const int p = (nh*5+j)*32 + m;
            if (p < 289){
                const int swz = (p&7)<<4;
                #pragma unroll
                for (int rg=0;rg<4;rg++){
                    const int ch0 = wo*32 + 8*rg + 4*hi;
                    const float v0 = gelu_q(acc[j][4*rg+0] + b4[rg].x);
                    const float v1 = gelu_q(acc[j][4*rg+1] + b4[rg].y);
                    const float v2 = gelu_q(acc[j][4*rg+2] + b4[rg].z);
                    const float v3 = gelu_q(acc[j][4*rg+3] + b4[rg].w);
                    *(uint2*)(sC1 + p*128 + ((2*ch0) ^ swz)) = make_uint2(pack2(v0,v1), pack2(v2,v3));
                }
            }
        }
    }
    __syncthreads();

    // ---- conv2 + gelu + gauss ----
    const short8* Ap2 = Ap1 + 4608;
    #pragma unroll
    for (int j=0;j<5;j++) acc[j] = 0.f;
    STEM_CONV32(sC1, Ap2)

    {
        float4 b4[4];
        #pragma unroll
        for (int rg=0;rg<4;rg++) b4[rg] = *(const float4*)(st2_b + wo*32 + 8*rg + 4*hi);
        float s[16];
        #pragma unroll
        for (int r=0;r<16;r++) s[r]=0.f;
        #pragma unroll
        for (int j=0;j<5;j++){
            const int p = (nh*5+j)*32 + m;
            if (p < 289){
                const int py = (p*241)>>12;
                const int px = p - py*17;
                const float ty = -1.f + 0.125f*py;
                const float tx = -1.f + 0.125f*px;
                const float g = expf(-3.125f*(ty*ty + tx*tx));
                #pragma unroll
                for (int rg=0;rg<4;rg++){
                    s[4*rg+0] += g*gelu_q(acc[j][4*rg+0] + b4[rg].x);
                    s[4*rg+1] += g*gelu_q(acc[j][4*rg+1] + b4[rg].y);
                    s[4*rg+2] += g*gelu_q(acc[j][4*rg+2] + b4[rg].z);
                    s[4*rg+3] += g*gelu_q(acc[j][4*rg+3] + b4[rg].w);
                }
            }
        }
        #pragma unroll
        for (int off=1; off<32; off<<=1){
            #pragma unroll
            for (int r=0;r<16;r++) s[r] += __shfl_xor(s[r], off);
        }
        if (m == 0){
            #pragma unroll
            for (int rg=0;rg<4;rg++)
                #pragma unroll
                for (int e=0;e<4;e++)
                    redS[wo*32 + 8*rg + 4*hi + e][nh] = s[4*rg+e];
        }
    }
    __syncthreads();
    if (t < 64){
        float Sv = 0.f;
        #pragma unroll
        for (int j=0;j<17;j++){
            const float tj = -1.f + 0.125f*j;
            Sv += expf(-3.125f*tj*tj);
        }
        vec_out[n*192+128+t] = (redS[t][0] + redS[t][1]) / (Sv*Sv);
    }
}

// ---------------- Head: 16 samples/block (proven) ----------------
__global__ __launch_bounds__(128) void head16_kernel(
    const float* __restrict__ vec, const float* __restrict__ p2s,
    const float* __restrict__ h1_w, const float* __restrict__ h1_b,
    const float* __restrict__ h2_w, const float* __restrict__ h2_b,
    const float* __restrict__ h3_w, const float* __restrict__ h3_b,
    float* __restrict__ out, int N)
{
    __shared__ float v[16][192];
    __shared__ float x1s[16][132];
    __shared__ float x2s[16][132];
    __shared__ float o3s[16][4];
    const int n0 = blockIdx.x*16, t = threadIdx.x;

    for (int idx=t; idx<16*192; idx+=128){
        const int s = idx/192, k = idx - s*192;
        v[s][k] = vec[n0*192 + idx];
    }
    __syncthreads();
    {
        const int o = t;
        float acc[16];
        const float b = h1_b[o];
        #pragma unroll
        for (int s=0;s<16;s++) acc[s]=b;
        const float4* wr = (const float4*)(h1_w + o*192);
        for (int k4=0;k4<48;k4++){
            const float4 wv4 = wr[k4];
            #pragma unroll
            for (int s=0;s<16;s++){
                const float4 vv = *(const float4*)&v[s][k4*4];
                acc[s] += wv4.x*vv.x + wv4.y*vv.y + wv4.z*vv.z + wv4.w*vv.w;
            }
        }
        #pragma unroll
        for (int s=0;s<16;s++) x1s[s][o] = gelu_f(acc[s]);
    }
    __syncthreads();
    {
        const int o = t;
        float acc[16];
        const float b = h2_b[o];
        #pragma unroll
        for (int s=0;s<16;s++) acc[s]=b;
        const float4* wr = (const float4*)(h2_w + o*128);
        for (int k4=0;k4<32;k4++){
            const float4 wv4 = wr[k4];
            #pragma unroll
            for (int s=0;s<16;s++){
                const float4 vv = *(const float4*)&x1s[s][k4*4];
                acc[s] += wv4.x*vv.x + wv4.y*vv.y + wv4.z*vv.z + wv4.w*vv.w;
            }
        }
        #pragma unroll
        for (int s=0;s<16;s++) x2s[s][o] = gelu_f(acc[s]);
    }
    __syncthreads();
    if (t < 48){
        const int j = t>>4, s = t&15;
        float a = h3_b[j];
        const float* wr = h3_w + j*128;
        for (int k=0;k<128;k++) a += x2s[s][k]*wr[k];
        o3s[s][j] = a;
    }
    __syncthreads();
    if (t < 16){
        const int s = t, n = n0 + s;
        const float dx = o3s[s][0], dy = o3s[s][1];
        float ls = o3s[s][2];
        ls = ls < -6.f ? -6.f : (ls > 3.f ? 3.f : ls);
        const float s0 = p2s[n*4+0]*dx + p2s[n*4+1]*dy;
        const float s1 = p2s[n*4+2]*dx + p2s[n*4+3]*dy;
        const float conf = 1.0f/fmaxf(expf(ls), 1e-4f);
        out[2*n]   = s0;
        out[2*n+1] = s1;
        out[2*N+n] = dx;
        out[3*N+n] = dy;
        out[4*N+n] = ls;
        out[5*N+n] = conf;
    }
}

extern "C" void kernel_launch(void* const* d_in, const int* in_sizes, int n_in,
                              void* d_out, int out_size, void* d_ws, size_t ws_size,
                              hipStream_t stream)
{
    (void)n_in; (void)out_size;
    const float* bottleneck = (const float*)d_in[0];
    const float* vis        = (const float*)d_in[1];
    const float* pos        = (const float*)d_in[2];
    const float* p2s        = (const float*)d_in[3];
    const float* dw_w  = (const float*)d_in[8];
    const float* dw_b  = (const float*)d_in[9];
    const float* ln_g  = (const float*)d_in[10];
    const float* ln_b  = (const float*)d_in[11];
    const float* pw1_w = (const float*)d_in[12];
    const float* pw1_b = (const float*)d_in[13];
    const float* pw2_w = (const float*)d_in[14];
    const float* pw2_b = (const float*)d_in[15];
    const float* gam   = (const float*)d_in[16];
    const float* b1w   = (const float*)d_in[17];
    const float* b1b   = (const float*)d_in[18];
    const float* s1w   = (const float*)d_in[19];
    const float* s1b   = (const float*)d_in[20];
    const float* s2w   = (const float*)d_in[21];
    const float* s2b   = (const float*)d_in[22];
    const float* h1w   = (const float*)d_in[23];
    const float* h1b   = (const float*)d_in[24];
    const float* h2w   = (const float*)d_in[25];
    const float* h2b   = (const float*)d_in[26];
    const float* h3w   = (const float*)d_in[27];
    const float* h3b   = (const float*)d_in[28];

    const int N = in_sizes[2]/2;            // 4096
    float* vec = (float*)d_ws;              // [N][192] f32
    const size_t vec_bytes = (size_t)N*192*sizeof(float);
    unsigned short* Apack = (unsigned short*)((char*)d_ws + vec_bytes);  // stem: 147456 B
    unsigned short* P1 = Apack + 73728;
    unsigned short* P2 = P1 + 262144;
    unsigned short* Pb = P2 + 262144;
    const size_t need = vec_bytes + 147456u + (262144u+262144u+32768u)*2u;

    hipMemsetAsync(d_ws, 0, vec_bytes, stream);

    prepack_kernel<<<36, 256, 0, stream>>>(s1w, s2w, Apack);

    if (ws_size >= need){
        prepack_bn_kernel<<<272, 256, 0, stream>>>(pw1_w, pw2_w, b1w, P1, P2, Pb);
        bn_branch_mfma<<<N/2, 512, 0, stream>>>(bottleneck, pos, dw_w, dw_b, ln_g, ln_b,
                                                pw1_b, pw2_b, gam, b1b,
                                                (const short8*)P1, (const short8*)P2, (const short8*)Pb,
                                                vec);
    } else {
        bn_branch_valu<<<N, 256, 0, stream>>>(bottleneck, pos, dw_w, dw_b, ln_g, ln_b,
                                              pw1_w, pw1_b, pw2_w, pw2_b, gam, b1w, b1b, vec);
    }
    stem_branch_kernel<<<N, 256, 0, stream>>>(vis, pos, (const short8*)Apack, s1b, s2b, vec);
    head16_kernel<<<N/16, 128, 0, stream>>>(vec, p2s, h1w, h1b, h2w, h2b, h3w, h3b,
                                            (float*)d_out, N);
}